// Round 1
// 645.398 us; speedup vs baseline: 1.0471x; 1.0471x over previous
//
#include <hip/hip_runtime.h>
#include <hip/hip_bf16.h>

typedef short short8 __attribute__((ext_vector_type(8)));
typedef float f32x4 __attribute__((ext_vector_type(4)));
typedef unsigned short u16;

#define BK 32
// Swizzled LDS layout for scatter-staged operands (MA==1 path only):
// element (row,k) at row*32 + ((k>>3) ^ ((row>>3)&3))*8 + (k&7); caps scatter
// write conflicts at 4-way (proven earlier: 1.92e8 -> 4.09e7 conflict cycles).
static __device__ __forceinline__ int sw(int row, int g) {
  return row * 32 + ((g ^ ((row >> 3) & 3)) << 3);
}

// fp32 -> bf16 round-to-nearest-even (payload as u16)
static __device__ __forceinline__ u16 f2b(float f) {
  union { float f; unsigned u; } x; x.f = f;
  unsigned r = x.u + 0x7FFF + ((x.u >> 16) & 1);
  return (u16)(r >> 16);
}
static __device__ __forceinline__ float b2f(u16 u) {
  unsigned int x = ((unsigned int)u) << 16;
  float f; __builtin_memcpy(&f, &x, 4);
  return f;
}

// Load 8 consecutive elements as bf16 payloads.
static __device__ __forceinline__ void load8(const u16* p, u16* dst) {
  union { uint4 u; u16 h[8]; } t;
  t.u = *(const uint4*)p;
  #pragma unroll
  for (int j = 0; j < 8; ++j) dst[j] = t.h[j];
}
static __device__ __forceinline__ void load8(const float* p, u16* dst) {
  float4 a = ((const float4*)p)[0];
  float4 b = ((const float4*)p)[1];
  dst[0] = f2b(a.x); dst[1] = f2b(a.y); dst[2] = f2b(a.z); dst[3] = f2b(a.w);
  dst[4] = f2b(b.x); dst[5] = f2b(b.y); dst[6] = f2b(b.z); dst[7] = f2b(b.w);
}

// Async global->LDS, 16B per lane (gfx950 global_load_lds_dwordx4).
// LDS dest must be wave-uniform base + lane*16 (m104/m108 caveat).
static __device__ __forceinline__ void gl_lds16(const u16* g, u16* l) {
  __builtin_amdgcn_global_load_lds(
      (const __attribute__((address_space(1))) unsigned int*)g,
      (__attribute__((address_space(3))) unsigned int*)l, 16, 0, 0);
}

// ---------------------------------------------------------------------------
// 128x128x32 MFMA GEMM (m97 structure): C[z] = (A[z] @ B[z]) * alpha + bias
// Staging modes per operand:
//   0 DIRECT : bf16, k-contiguous rows (A:[M][K], B:[N][K]); global_load_lds.
//   1 SCATTER: k-strided ([K][M]), u16; swizzled scalar scatter into LDS.
// 4 waves (2x2), each computes 64x64 = 4x4 MFMAs of 16x16x32.
// Verified fragment maps (m89/m91): A: m=lane&15,k=(lane>>4)*8+j;
// B: n=lane&15; C/D: row=(lane>>4)*4+r, col=lane&15.
// ---------------------------------------------------------------------------
template<int MA, int MB, typename OutT>
__global__ __launch_bounds__(256) void gemm128(
    const u16* __restrict__ A, const u16* __restrict__ B,
    const float* __restrict__ bias, const float* __restrict__ alpha_ptr,
    OutT* __restrict__ C, int K, int lda, int ldb, int ldc,
    long long sA, long long sB, long long sC)
{
  __shared__ u16 As[128 * 32];  // 8 KB
  __shared__ u16 Bs[128 * 32];  // 8 KB

  A += (long long)blockIdx.z * sA;
  B += (long long)blockIdx.z * sB;
  C += (long long)blockIdx.z * sC;

  const int tid  = threadIdx.x;
  const int m0   = blockIdx.y * 128;
  const int n0   = blockIdx.x * 128;
  const int w    = tid >> 6, lane = tid & 63;
  const int wm   = (w >> 1) * 64;   // wave row origin in tile
  const int wn   = (w & 1) * 64;    // wave col origin in tile
  const int lrow = lane & 15;
  const int lg   = lane >> 4;       // k-granule 0..3

  // k0-invariant fragment read offsets (mode-dependent layout)
  int aoff[4], boff[4];
  #pragma unroll
  for (int t = 0; t < 4; ++t) {
    const int ar = wm + t * 16 + lrow;
    const int br = wn + t * 16 + lrow;
    aoff[t] = (MA == 1) ? sw(ar, lg) : ar * 32 + lg * 8;
    boff[t] = (MB == 1) ? sw(br, lg) : br * 32 + lg * 8;
  }

  f32x4 acc[4][4] = {};

  for (int k0 = 0; k0 < K; k0 += BK) {
    // ---- stage A tile (128 x 32) ----
    if constexpr (MA == 0) {
      gl_lds16(A + (long long)(m0 + (tid >> 2)) * lda + (k0 + (tid & 3) * 8),
               As + tid * 8);
      gl_lds16(A + (long long)(m0 + 64 + (tid >> 2)) * lda + (k0 + (tid & 3) * 8),
               As + 2048 + tid * 8);
    } else {  // SCATTER: k-strided [K][M]
      const int kk = tid >> 3;
      #pragma unroll
      for (int p = 0; p < 2; ++p) {
        const int rr = (tid & 7) * 8 + p * 64;
        u16 h[8];
        load8(A + (long long)(k0 + kk) * lda + (m0 + rr), h);
        #pragma unroll
        for (int j = 0; j < 8; ++j) As[sw(rr + j, kk >> 3) + (kk & 7)] = h[j];
      }
    }
    // ---- stage B tile (128 x 32) ----
    if constexpr (MB == 0) {
      gl_lds16(B + (long long)(n0 + (tid >> 2)) * ldb + (k0 + (tid & 3) * 8),
               Bs + tid * 8);
      gl_lds16(B + (long long)(n0 + 64 + (tid >> 2)) * ldb + (k0 + (tid & 3) * 8),
               Bs + 2048 + tid * 8);
    } else {
      const int kk = tid >> 3;
      #pragma unroll
      for (int p = 0; p < 2; ++p) {
        const int rr = (tid & 7) * 8 + p * 64;
        u16 h[8];
        load8(B + (long long)(k0 + kk) * ldb + (n0 + rr), h);
        #pragma unroll
        for (int j = 0; j < 8; ++j) Bs[sw(rr + j, kk >> 3) + (kk & 7)] = h[j];
      }
    }
    __syncthreads();

    short8 af[4], bf[4];
    #pragma unroll
    for (int t = 0; t < 4; ++t) af[t] = *(const short8*)(As + aoff[t]);
    #pragma unroll
    for (int t = 0; t < 4; ++t) bf[t] = *(const short8*)(Bs + boff[t]);
    #pragma unroll
    for (int mt = 0; mt < 4; ++mt)
      #pragma unroll
      for (int nt = 0; nt < 4; ++nt)
        acc[mt][nt] = __builtin_amdgcn_mfma_f32_16x16x32_bf16(
            af[mt], bf[nt], acc[mt][nt], 0, 0, 0);
    __syncthreads();
  }

  const float alpha = alpha_ptr ? *alpha_ptr : 1.0f;
  #pragma unroll
  for (int nt = 0; nt < 4; ++nt) {
    const int n = n0 + wn + nt * 16 + lrow;
    const float bv = bias ? bias[n] : 0.0f;
    #pragma unroll
    for (int mt = 0; mt < 4; ++mt) {
      #pragma unroll
      for (int r = 0; r < 4; ++r) {
        const int m = m0 + wm + mt * 16 + lg * 4 + r;
        C[(long long)m * ldc + n] = OutT(acc[mt][nt][r] * alpha + bv);
      }
    }
  }
}

// ---------------------------------------------------------------------------
// Tiled 64x64 transpose with optional fp32->bf16 convert.
// in: [z][R][C] (T = float or u16/bf16 payload), out: [z][C][R] bf16.
// Coalesced global load/store; contiguous LDS write, ~2-way-conflict gather.
// ---------------------------------------------------------------------------
template<typename T>
__global__ __launch_bounds__(256) void transpose_kernel(
    const T* __restrict__ in, u16* __restrict__ out, int R, int C,
    long long sIn, long long sOut)
{
  __shared__ u16 t[64][66];
  in  += (long long)blockIdx.z * sIn;
  out += (long long)blockIdx.z * sOut;
  const int r0 = blockIdx.y * 64, c0 = blockIdx.x * 64;
  const int tid = threadIdx.x;
  const int rr = tid >> 3, cc = (tid & 7) * 8;  // rr 0..31
  #pragma unroll
  for (int p = 0; p < 2; ++p) {
    union { uint4 u; unsigned w[4]; u16 h[8]; } v;
    const int row = rr + p * 32;
    load8(in + (long long)(r0 + row) * C + (c0 + cc), v.h);
    #pragma unroll
    for (int k = 0; k < 4; ++k)
      *(unsigned*)&t[row][cc + k * 2] = v.w[k];
  }
  __syncthreads();
  #pragma unroll
  for (int p = 0; p < 2; ++p) {
    const int oc = (tid >> 3) + p * 32;
    const int rc = (tid & 7) * 8;
    union { uint4 u; u16 h[8]; } g;
    #pragma unroll
    for (int j = 0; j < 8; ++j) g.h[j] = t[rc + j][oc];
    *(uint4*)(out + (long long)(c0 + oc) * R + (r0 + rc)) = g.u;
  }
}

// ---------------------------------------------------------------------------
// Elementwise fp32 -> bf16 convert (row-major), 8 elems/thread/iter.
// ---------------------------------------------------------------------------
__global__ __launch_bounds__(256) void cvt_kernel(
    const float* __restrict__ in, u16* __restrict__ out, int n8)
{
  const int stride = gridDim.x * 256;
  for (int i = blockIdx.x * 256 + threadIdx.x; i < n8; i += stride) {
    union { uint4 u; u16 h[8]; } v;
    load8(in + (long long)i * 8, v.h);
    *(uint4*)(out + (long long)i * 8) = v.u;
  }
}

// ---------------------------------------------------------------------------
// LayerNorm + ReLU over rows of 768 fp32 -> OutT. ReLU propagates NaN.
// ---------------------------------------------------------------------------
template<typename OutT>
__global__ __launch_bounds__(256) void ln_relu_kernel(
    const float* __restrict__ x, const float* __restrict__ g,
    const float* __restrict__ beta, OutT* __restrict__ out)
{
  __shared__ float sa[4], sb[4];
  const float* xr = x + (long long)blockIdx.x * 768;
  float v[3]; float s = 0.f, ss = 0.f;
  #pragma unroll
  for (int j = 0; j < 3; ++j) {
    v[j] = xr[threadIdx.x + j * 256];
    s += v[j]; ss += v[j] * v[j];
  }
  #pragma unroll
  for (int off = 32; off; off >>= 1) {
    s  += __shfl_down(s, off);
    ss += __shfl_down(ss, off);
  }
  const int w = threadIdx.x >> 6, lane = threadIdx.x & 63;
  if (!lane) { sa[w] = s; sb[w] = ss; }
  __syncthreads();
  s  = sa[0] + sa[1] + sa[2] + sa[3];
  ss = sb[0] + sb[1] + sb[2] + sb[3];
  const float mean = s * (1.f / 768.f);
  const float var  = ss * (1.f / 768.f) - mean * mean;
  const float rst  = rsqrtf(var + 1e-5f);
  OutT* orow = out + (long long)blockIdx.x * 768;
  #pragma unroll
  for (int j = 0; j < 3; ++j) {
    const int idx = threadIdx.x + j * 256;
    const float yv = (v[j] - mean) * rst * g[idx] + beta[idx];
    const float rv = (yv <= 0.f) ? 0.f : yv;  // NaN -> yv (propagates)
    orow[idx] = OutT(rv);
  }
}

// ---------------------------------------------------------------------------
// In-place row softmax over 2048 bf16 values (fp32 math)
// ---------------------------------------------------------------------------
__global__ __launch_bounds__(256) void softmax_kernel(u16* __restrict__ sim)
{
  __shared__ float sm[4], ssum[4];
  u16* row = sim + (long long)blockIdx.x * 2048;
  union { uint4 u; u16 h[8]; } v;
  v.u = *(const uint4*)(row + threadIdx.x * 8);
  float f[8]; float mx = -1e30f;
  #pragma unroll
  for (int j = 0; j < 8; ++j) { f[j] = b2f(v.h[j]); mx = fmaxf(mx, f[j]); }
  #pragma unroll
  for (int off = 32; off; off >>= 1) mx = fmaxf(mx, __shfl_down(mx, off));
  const int w = threadIdx.x >> 6, lane = threadIdx.x & 63;
  if (!lane) sm[w] = mx;
  __syncthreads();
  mx = fmaxf(fmaxf(sm[0], sm[1]), fmaxf(sm[2], sm[3]));
  float s = 0.f;
  #pragma unroll
  for (int j = 0; j < 8; ++j) { f[j] = __expf(f[j] - mx); s += f[j]; }
  #pragma unroll
  for (int off = 32; off; off >>= 1) s += __shfl_down(s, off);
  if (!lane) ssum[w] = s;
  __syncthreads();
  s = ssum[0] + ssum[1] + ssum[2] + ssum[3];
  const float inv = 1.f / s;
  #pragma unroll
  for (int j = 0; j < 8; ++j) v.h[j] = f2b(f[j] * inv);
  *(uint4*)(row + threadIdx.x * 8) = v.u;
}

// ---------------------------------------------------------------------------
// claw mean, two deterministic stages
// ---------------------------------------------------------------------------
__global__ __launch_bounds__(256) void claw_partial_kernel(
    const float* __restrict__ claw, float* __restrict__ partial, int n)
{
  __shared__ float sa[4];
  float s = 0.f;
  const int nv = n >> 2;
  for (int i = blockIdx.x * 256 + threadIdx.x; i < nv; i += 64 * 256) {
    float4 v = ((const float4*)claw)[i];
    s += v.x + v.y + v.z + v.w;
  }
  #pragma unroll
  for (int off = 32; off; off >>= 1) s += __shfl_down(s, off);
  const int w = threadIdx.x >> 6, lane = threadIdx.x & 63;
  if (!lane) sa[w] = s;
  __syncthreads();
  if (threadIdx.x == 0)
    partial[blockIdx.x] = sa[0] + sa[1] + sa[2] + sa[3];
}

__global__ void claw_final_kernel(
    const float* __restrict__ partial, float* __restrict__ scale, float inv)
{
  float s = partial[threadIdx.x];
  #pragma unroll
  for (int off = 32; off; off >>= 1) s += __shfl_down(s, off);
  if (threadIdx.x == 0) *scale = s * inv;
}

// ---------------------------------------------------------------------------
extern "C" void kernel_launch(void* const* d_in, const int* in_sizes, int n_in,
                              void* d_out, int out_size, void* d_ws, size_t ws_size,
                              hipStream_t stream)
{
  const float* vis   = (const float*)d_in[0];
  const float* lang  = (const float*)d_in[1];
  const float* vW    = (const float*)d_in[2];
  const float* vb    = (const float*)d_in[3];
  const float* vg    = (const float*)d_in[4];
  const float* vbeta = (const float*)d_in[5];
  const float* lW    = (const float*)d_in[6];
  const float* lb    = (const float*)d_in[7];
  const float* lg    = (const float*)d_in[8];
  const float* lbeta = (const float*)d_in[9];
  const float* claw  = (const float*)d_in[10];
  const float* oW    = (const float*)d_in[11];
  const float* ob    = (const float*)d_in[12];
  const float* og    = (const float*)d_in[13];
  const float* obeta = (const float*)d_in[14];
  float* out = (float*)d_out;

  constexpr int NB = 8, S = 2048, D = 768;
  constexpr int R = NB * S;                       // 16384
  constexpr long long SD = (long long)S * D;      // 1,572,864
  constexpr long long SS = (long long)S * S;      // 4,194,304
  const int nclaw = in_sizes[10];
  const float claw_inv = 1.0f / ((float)nclaw * 0.07f);
  const dim3 blk(256);

  // Workspace layout (peak 167,772,432 B == proven floor from prior rounds).
  // Lifetimes:
  //   [0,25.2M)      vp            -> comb (after sim GEMM; vp dead then)
  //   [25.2M,50.3M)  lp            -> comb upper half
  //   [50.3M,75.5M)  visb (v-proj) -> vpT (after v-LN)
  //   [75.5M,100.7M) langb (l-proj)-> lpT (after l-LN)
  //   [100.7M,167.8M) y fp32 (50.3M, proj+out) / sim bf16 (67.1M)
  //   [151.0M,153.4M) vWT+lWT (early, dead before sim GEMM writes here)
  //                   oWT (re-created after aligned GEMMs, before out GEMM)
  char* ws = (char*)d_ws;
  u16*   vp    = (u16*)  (ws);
  u16*   lp    = (u16*)  (ws + 25165824);
  u16*   visb  = (u16*)  (ws + 50331648);
  u16*   vpT   = (u16*)  (ws + 50331648);
  u16*   langb = (u16*)  (ws + 75497472);
  u16*   lpT   = (u16*)  (ws + 75497472);
  u16*   sim   = (u16*)  (ws + 100663296);
  float* y     = (float*)(ws + 100663296);
  u16*   vWT   = (u16*)  (ws + 150994944);
  u16*   lWT   = vWT + 589824;          // 768*768 payloads
  u16*   oWT   = (u16*)  (ws + 150994944);
  u16*   comb  = (u16*)  (ws);
  float* scale   = (float*)(ws + 167772160);
  float* partial = (float*)(ws + 167772176);

  claw_partial_kernel<<<64, blk, 0, stream>>>(claw, partial, nclaw);
  claw_final_kernel<<<1, 64, 0, stream>>>(partial, scale, claw_inv);

  // Weight transposes: W[k][n] fp32 -> WT[n][k] bf16 (direct B operands)
  transpose_kernel<float><<<dim3(12, 12, 1), blk, 0, stream>>>(
      vW, vWT, D, D, 0, 0);
  transpose_kernel<float><<<dim3(12, 12, 1), blk, 0, stream>>>(
      lW, lWT, D, D, 0, 0);

  // vision: visb = bf16(vis); y = visb @ vWT^T + vb; vp = relu(LN(y)); vpT
  cvt_kernel<<<2048, blk, 0, stream>>>(vis, visb, (int)(R * D / 8));
  gemm128<0, 0, float><<<dim3(D / 128, R / 128, 1), blk, 0, stream>>>(
      visb, vWT, vb, nullptr, y, D, D, D, D, 0, 0, 0);
  ln_relu_kernel<__hip_bfloat16><<<R, blk, 0, stream>>>(
      y, vg, vbeta, (__hip_bfloat16*)vp);
  transpose_kernel<u16><<<dim3(D / 64, S / 64, NB), blk, 0, stream>>>(
      vp, vpT, S, D, SD, SD);

  // language
  cvt_kernel<<<2048, blk, 0, stream>>>(lang, langb, (int)(R * D / 8));
  gemm128<0, 0, float><<<dim3(D / 128, R / 128, 1), blk, 0, stream>>>(
      langb, lWT, lb, nullptr, y, D, D, D, D, 0, 0, 0);
  ln_relu_kernel<__hip_bfloat16><<<R, blk, 0, stream>>>(
      y, lg, lbeta, (__hip_bfloat16*)lp);
  transpose_kernel<u16><<<dim3(D / 64, S / 64, NB), blk, 0, stream>>>(
      lp, lpT, S, D, SD, SD);

  // sim[z] = (vp[z] @ lp[z]^T) * scale   (both DIRECT)
  gemm128<0, 0, __hip_bfloat16><<<dim3(S / 128, S / 128, NB), blk, 0, stream>>>(
      vp, lp, nullptr, scale, (__hip_bfloat16*)sim, D, D, D, S, SD, SD, SS);
  softmax_kernel<<<R, blk, 0, stream>>>(sim);

  // aligned_vision[z] = A[z] @ vp[z] -> comb[:, 0:768]  (both DIRECT via vpT)
  gemm128<0, 0, __hip_bfloat16><<<dim3(D / 128, S / 128, NB), blk, 0, stream>>>(
      sim, vpT, nullptr, nullptr, (__hip_bfloat16*)comb,
      S, S, S, 2 * D, SS, SD, 2 * SD);
  // aligned_language[z] = A[z]^T @ lp[z] -> comb[:, 768:1536]
  // (A scatter over sim; B DIRECT via lpT)
  gemm128<1, 0, __hip_bfloat16><<<dim3(D / 128, S / 128, NB), blk, 0, stream>>>(
      sim, lpT, nullptr, nullptr, (__hip_bfloat16*)comb + D,
      S, S, S, 2 * D, SS, SD, 2 * SD);

  // oWT (sim region dead past here except y overlay; [151.0M,153.4M) free)
  transpose_kernel<float><<<dim3(12, 24, 1), blk, 0, stream>>>(
      oW, oWT, 2 * D, D, 0, 0);

  // out = relu(LN(comb @ oWT^T + ob))   (both DIRECT; y over dead sim)
  gemm128<0, 0, float><<<dim3(D / 128, R / 128, 1), blk, 0, stream>>>(
      comb, oWT, ob, nullptr, y, 2 * D, 2 * D, 2 * D, D, 0, 0, 0);
  ln_relu_kernel<float><<<R, blk, 0, stream>>>(y, og, obeta, out);
}

// Round 2
// 625.681 us; speedup vs baseline: 1.0801x; 1.0315x over previous
//
#include <hip/hip_runtime.h>
#include <hip/hip_bf16.h>

typedef short short8 __attribute__((ext_vector_type(8)));
typedef float f32x4 __attribute__((ext_vector_type(4)));
typedef unsigned short u16;

#define BK 32
// Swizzled LDS layout for scatter-staged operands (gemm128 MA==1 path only).
static __device__ __forceinline__ int sw(int row, int g) {
  return row * 32 + ((g ^ ((row >> 3) & 3)) << 3);
}

// fp32 -> bf16 round-to-nearest-even (payload as u16)
static __device__ __forceinline__ u16 f2b(float f) {
  union { float f; unsigned u; } x; x.f = f;
  unsigned r = x.u + 0x7FFF + ((x.u >> 16) & 1);
  return (u16)(r >> 16);
}
static __device__ __forceinline__ float b2f(u16 u) {
  unsigned int x = ((unsigned int)u) << 16;
  float f; __builtin_memcpy(&f, &x, 4);
  return f;
}

static __device__ __forceinline__ void load8(const u16* p, u16* dst) {
  union { uint4 u; u16 h[8]; } t;
  t.u = *(const uint4*)p;
  #pragma unroll
  for (int j = 0; j < 8; ++j) dst[j] = t.h[j];
}
static __device__ __forceinline__ void load8(const float* p, u16* dst) {
  float4 a = ((const float4*)p)[0];
  float4 b = ((const float4*)p)[1];
  dst[0] = f2b(a.x); dst[1] = f2b(a.y); dst[2] = f2b(a.z); dst[3] = f2b(a.w);
  dst[4] = f2b(b.x); dst[5] = f2b(b.y); dst[6] = f2b(b.z); dst[7] = f2b(b.w);
}

// Async global->LDS, 16B per lane (gfx950 global_load_lds_dwordx4).
// LDS dest must be wave-uniform base + lane*16 (m104/m108 caveat).
static __device__ __forceinline__ void gl_lds16(const u16* g, u16* l) {
  __builtin_amdgcn_global_load_lds(
      (const __attribute__((address_space(1))) unsigned int*)g,
      (__attribute__((address_space(3))) unsigned int*)l, 16, 0, 0);
}

// ---------------------------------------------------------------------------
// 256x256x64 8-phase pipelined MFMA GEMM (m201-style):
//   C[z] = (A[z] @ B[z]^T) * alpha + bias, A:[M][K], B:[N][K], bf16 payloads.
// 512 threads = 8 waves (2M x 4N); per-wave output 128x64 = 8x4 16x16 frags.
// LDS: A,B each 2 x 256x64 bf16 (dbuf) = 128 KiB total.
// Per K-tile: 4 phases {ds_read A-quadrant (+all B at P1) | issue prefetch |
//   barrier | setprio(1) 16 MFMA setprio(0) | barrier}; counted vmcnt(3) once
//   per K-tile (never 0 in loop) - 3 A-chunk loads of tile t+2 stay in flight.
// Swizzle (T2): element granule ^ ((row>>2)&1)<<1; applied as inverse-swizzled
//   GLOBAL source + swizzled ds_read; gl_lds dest stays linear (rule #21).
// Prefetch targets only LDS regions freed by the PREVIOUS phase's reads
//   (reads complete before each phase's 2nd barrier via consuming MFMAs):
//   A-chunk c of tile tau = rows {32c..+32}u{128+32c..+32} of buf[tau&1],
//   freed by phase c of group tau-2; B halves freed wholesale at group end.
// Issue schedule per group t: P1: A3(t+1)+Bh0(t+1); P2: Bh1(t+1)+A0(t+2);
//   P3: A1(t+2); P4: A2(t+2); then vmcnt(3)+barrier.
// Requires: M,N % 256 == 0, K % 128 == 0 (NT even, NT >= 2).
// ---------------------------------------------------------------------------
template<typename OutT>
__global__ __launch_bounds__(512, 2) void gemm256(
    const u16* __restrict__ A, const u16* __restrict__ B,
    const float* __restrict__ bias, const float* __restrict__ alpha_ptr,
    OutT* __restrict__ C, int K, int lda, int ldb, int ldc,
    long long sA, long long sB, long long sC)
{
  __shared__ u16 As[2][256 * 64];  // 64 KB
  __shared__ u16 Bs[2][256 * 64];  // 64 KB

  A += (long long)blockIdx.z * sA;
  B += (long long)blockIdx.z * sB;
  C += (long long)blockIdx.z * sC;

  const int tid  = threadIdx.x;
  const int m0   = blockIdx.y * 256;
  const int n0   = blockIdx.x * 256;
  const int w    = tid >> 6, lane = tid & 63;
  const int wm   = (w >> 2) * 128;   // 0 / 128
  const int wn   = (w & 3) * 64;     // 0..192
  const int lrow = lane & 15;
  const int lg   = lane >> 4;                    // k-granule 0..3
  const int xe   = ((lrow >> 2) & 1) << 1;       // read-side granule xor
  const int sr   = tid >> 3;                     // staging row-lane 0..63
  const int srcg = (tid & 7) ^ ((tid >> 4) & 2); // inverse-swizzled src granule
  const int NT   = K >> 6;

  f32x4 acc[8][4] = {};

  // --- staging slots (each gl_lds dest is linear: base + tid*16 bytes) ---
  auto stA = [&](int t, int c) {
    u16* lb = As[t & 1];
    const int r = (sr < 32) ? (32 * c + sr) : (96 + 32 * c + sr);
    gl_lds16(A + (long long)(m0 + r) * lda + (t * 64 + srcg * 8),
             lb + r * 64 + (tid & 7) * 8);
  };
  auto stB = [&](int t, int h) {
    u16* lb = Bs[t & 1];
    #pragma unroll
    for (int l = 0; l < 2; ++l) {
      const int r = 128 * h + 64 * l + sr;
      gl_lds16(B + (long long)(n0 + r) * ldb + (t * 64 + srcg * 8),
               lb + r * 64 + (tid & 7) * 8);
    }
  };
  auto rdA = [&](int t, int mt, int ks) -> short8 {
    const int r = wm + mt * 16 + lrow;
    return *(const short8*)(As[t & 1] + r * 64 + (((ks * 4 + lg) ^ xe) << 3));
  };
  auto rdB = [&](int t, int nt, int ks) -> short8 {
    const int r = wn + nt * 16 + lrow;
    return *(const short8*)(Bs[t & 1] + r * 64 + (((ks * 4 + lg) ^ xe) << 3));
  };

  // --- prologue: tile0 complete + tile1's A0..A2 in flight (3 newest) ---
  #pragma unroll
  for (int c = 0; c < 4; ++c) stA(0, c);
  stB(0, 0); stB(0, 1);
  stA(1, 0); stA(1, 1); stA(1, 2);
  asm volatile("s_waitcnt vmcnt(3)" ::: "memory");
  __builtin_amdgcn_s_barrier();

  short8 bfr[4][2];
  for (int t = 0; t < NT; ++t) {
    short8 afr[2][2];
    // ---- P1: all B + A-quad0; prefetch A3(t+1), Bh0(t+1) ----
    #pragma unroll
    for (int nt = 0; nt < 4; ++nt) {
      bfr[nt][0] = rdB(t, nt, 0);
      bfr[nt][1] = rdB(t, nt, 1);
    }
    afr[0][0] = rdA(t, 0, 0); afr[0][1] = rdA(t, 0, 1);
    afr[1][0] = rdA(t, 1, 0); afr[1][1] = rdA(t, 1, 1);
    if (t + 1 < NT) { stA(t + 1, 3); stB(t + 1, 0); }
    __builtin_amdgcn_s_barrier();
    __builtin_amdgcn_s_setprio(1);
    #pragma unroll
    for (int j = 0; j < 2; ++j)
      #pragma unroll
      for (int nt = 0; nt < 4; ++nt)
        #pragma unroll
        for (int ks = 0; ks < 2; ++ks)
          acc[j][nt] = __builtin_amdgcn_mfma_f32_16x16x32_bf16(
              afr[j][ks], bfr[nt][ks], acc[j][nt], 0, 0, 0);
    __builtin_amdgcn_s_setprio(0);
    __builtin_amdgcn_s_barrier();
    // ---- P2: A-quad1; prefetch Bh1(t+1), A0(t+2) ----
    afr[0][0] = rdA(t, 2, 0); afr[0][1] = rdA(t, 2, 1);
    afr[1][0] = rdA(t, 3, 0); afr[1][1] = rdA(t, 3, 1);
    if (t + 1 < NT) stB(t + 1, 1);
    if (t + 2 < NT) stA(t + 2, 0);
    __builtin_amdgcn_s_barrier();
    __builtin_amdgcn_s_setprio(1);
    #pragma unroll
    for (int j = 0; j < 2; ++j)
      #pragma unroll
      for (int nt = 0; nt < 4; ++nt)
        #pragma unroll
        for (int ks = 0; ks < 2; ++ks)
          acc[2 + j][nt] = __builtin_amdgcn_mfma_f32_16x16x32_bf16(
              afr[j][ks], bfr[nt][ks], acc[2 + j][nt], 0, 0, 0);
    __builtin_amdgcn_s_setprio(0);
    __builtin_amdgcn_s_barrier();
    // ---- P3: A-quad2; prefetch A1(t+2) ----
    afr[0][0] = rdA(t, 4, 0); afr[0][1] = rdA(t, 4, 1);
    afr[1][0] = rdA(t, 5, 0); afr[1][1] = rdA(t, 5, 1);
    if (t + 2 < NT) stA(t + 2, 1);
    __builtin_amdgcn_s_barrier();
    __builtin_amdgcn_s_setprio(1);
    #pragma unroll
    for (int j = 0; j < 2; ++j)
      #pragma unroll
      for (int nt = 0; nt < 4; ++nt)
        #pragma unroll
        for (int ks = 0; ks < 2; ++ks)
          acc[4 + j][nt] = __builtin_amdgcn_mfma_f32_16x16x32_bf16(
              afr[j][ks], bfr[nt][ks], acc[4 + j][nt], 0, 0, 0);
    __builtin_amdgcn_s_setprio(0);
    __builtin_amdgcn_s_barrier();
    // ---- P4: A-quad3; prefetch A2(t+2); counted vmcnt + barrier ----
    afr[0][0] = rdA(t, 6, 0); afr[0][1] = rdA(t, 6, 1);
    afr[1][0] = rdA(t, 7, 0); afr[1][1] = rdA(t, 7, 1);
    if (t + 2 < NT) stA(t + 2, 2);
    __builtin_amdgcn_s_barrier();
    __builtin_amdgcn_s_setprio(1);
    #pragma unroll
    for (int j = 0; j < 2; ++j)
      #pragma unroll
      for (int nt = 0; nt < 4; ++nt)
        #pragma unroll
        for (int ks = 0; ks < 2; ++ks)
          acc[6 + j][nt] = __builtin_amdgcn_mfma_f32_16x16x32_bf16(
              afr[j][ks], bfr[nt][ks], acc[6 + j][nt], 0, 0, 0);
    __builtin_amdgcn_s_setprio(0);
    asm volatile("s_waitcnt vmcnt(3)" ::: "memory");
    __builtin_amdgcn_s_barrier();
  }

  const float alpha = alpha_ptr ? *alpha_ptr : 1.0f;
  #pragma unroll
  for (int nt = 0; nt < 4; ++nt) {
    const int n = n0 + wn + nt * 16 + lrow;
    const float bv = bias ? bias[n] : 0.0f;
    #pragma unroll
    for (int mt = 0; mt < 8; ++mt)
      #pragma unroll
      for (int r = 0; r < 4; ++r) {
        const int m = m0 + wm + mt * 16 + lg * 4 + r;
        C[(long long)m * ldc + n] = OutT(acc[mt][nt][r] * alpha + bv);
      }
  }
}

// ---------------------------------------------------------------------------
// 128x128x32 MFMA GEMM (m97 structure), kept for the A^T scatter case only.
//   MA==1: A is k-strided [K][M] (sim columns); swizzled scalar LDS scatter.
//   MB==0: B direct bf16 [N][K] via global_load_lds.
// ---------------------------------------------------------------------------
template<int MA, int MB, typename OutT>
__global__ __launch_bounds__(256) void gemm128(
    const u16* __restrict__ A, const u16* __restrict__ B,
    const float* __restrict__ bias, const float* __restrict__ alpha_ptr,
    OutT* __restrict__ C, int K, int lda, int ldb, int ldc,
    long long sA, long long sB, long long sC)
{
  __shared__ u16 As[128 * 32];
  __shared__ u16 Bs[128 * 32];

  A += (long long)blockIdx.z * sA;
  B += (long long)blockIdx.z * sB;
  C += (long long)blockIdx.z * sC;

  const int tid  = threadIdx.x;
  const int m0   = blockIdx.y * 128;
  const int n0   = blockIdx.x * 128;
  const int w    = tid >> 6, lane = tid & 63;
  const int wm   = (w >> 1) * 64;
  const int wn   = (w & 1) * 64;
  const int lrow = lane & 15;
  const int lg   = lane >> 4;

  int aoff[4], boff[4];
  #pragma unroll
  for (int t = 0; t < 4; ++t) {
    const int ar = wm + t * 16 + lrow;
    const int br = wn + t * 16 + lrow;
    aoff[t] = (MA == 1) ? sw(ar, lg) : ar * 32 + lg * 8;
    boff[t] = (MB == 1) ? sw(br, lg) : br * 32 + lg * 8;
  }

  f32x4 acc[4][4] = {};

  for (int k0 = 0; k0 < K; k0 += BK) {
    if constexpr (MA == 0) {
      gl_lds16(A + (long long)(m0 + (tid >> 2)) * lda + (k0 + (tid & 3) * 8),
               As + tid * 8);
      gl_lds16(A + (long long)(m0 + 64 + (tid >> 2)) * lda + (k0 + (tid & 3) * 8),
               As + 2048 + tid * 8);
    } else {
      const int kk = tid >> 3;
      #pragma unroll
      for (int p = 0; p < 2; ++p) {
        const int rr = (tid & 7) * 8 + p * 64;
        u16 h[8];
        load8(A + (long long)(k0 + kk) * lda + (m0 + rr), h);
        #pragma unroll
        for (int j = 0; j < 8; ++j) As[sw(rr + j, kk >> 3) + (kk & 7)] = h[j];
      }
    }
    if constexpr (MB == 0) {
      gl_lds16(B + (long long)(n0 + (tid >> 2)) * ldb + (k0 + (tid & 3) * 8),
               Bs + tid * 8);
      gl_lds16(B + (long long)(n0 + 64 + (tid >> 2)) * ldb + (k0 + (tid & 3) * 8),
               Bs + 2048 + tid * 8);
    } else {
      const int kk = tid >> 3;
      #pragma unroll
      for (int p = 0; p < 2; ++p) {
        const int rr = (tid & 7) * 8 + p * 64;
        u16 h[8];
        load8(B + (long long)(k0 + kk) * ldb + (n0 + rr), h);
        #pragma unroll
        for (int j = 0; j < 8; ++j) Bs[sw(rr + j, kk >> 3) + (kk & 7)] = h[j];
      }
    }
    __syncthreads();

    short8 af[4], bf[4];
    #pragma unroll
    for (int t = 0; t < 4; ++t) af[t] = *(const short8*)(As + aoff[t]);
    #pragma unroll
    for (int t = 0; t < 4; ++t) bf[t] = *(const short8*)(Bs + boff[t]);
    #pragma unroll
    for (int mt = 0; mt < 4; ++mt)
      #pragma unroll
      for (int nt = 0; nt < 4; ++nt)
        acc[mt][nt] = __builtin_amdgcn_mfma_f32_16x16x32_bf16(
            af[mt], bf[nt], acc[mt][nt], 0, 0, 0);
    __syncthreads();
  }

  const float alpha = alpha_ptr ? *alpha_ptr : 1.0f;
  #pragma unroll
  for (int nt = 0; nt < 4; ++nt) {
    const int n = n0 + wn + nt * 16 + lrow;
    const float bv = bias ? bias[n] : 0.0f;
    #pragma unroll
    for (int mt = 0; mt < 4; ++mt) {
      #pragma unroll
      for (int r = 0; r < 4; ++r) {
        const int m = m0 + wm + mt * 16 + lg * 4 + r;
        C[(long long)m * ldc + n] = OutT(acc[mt][nt][r] * alpha + bv);
      }
    }
  }
}

// ---------------------------------------------------------------------------
// Tiled 64x64 transpose with optional fp32->bf16 convert.
// ---------------------------------------------------------------------------
template<typename T>
__global__ __launch_bounds__(256) void transpose_kernel(
    const T* __restrict__ in, u16* __restrict__ out, int R, int C,
    long long sIn, long long sOut)
{
  __shared__ u16 t[64][66];
  in  += (long long)blockIdx.z * sIn;
  out += (long long)blockIdx.z * sOut;
  const int r0 = blockIdx.y * 64, c0 = blockIdx.x * 64;
  const int tid = threadIdx.x;
  const int rr = tid >> 3, cc = (tid & 7) * 8;
  #pragma unroll
  for (int p = 0; p < 2; ++p) {
    union { uint4 u; unsigned w[4]; u16 h[8]; } v;
    const int row = rr + p * 32;
    load8(in + (long long)(r0 + row) * C + (c0 + cc), v.h);
    #pragma unroll
    for (int k = 0; k < 4; ++k)
      *(unsigned*)&t[row][cc + k * 2] = v.w[k];
  }
  __syncthreads();
  #pragma unroll
  for (int p = 0; p < 2; ++p) {
    const int oc = (tid >> 3) + p * 32;
    const int rc = (tid & 7) * 8;
    union { uint4 u; u16 h[8]; } g;
    #pragma unroll
    for (int j = 0; j < 8; ++j) g.h[j] = t[rc + j][oc];
    *(uint4*)(out + (long long)(c0 + oc) * R + (r0 + rc)) = g.u;
  }
}

// ---------------------------------------------------------------------------
// Elementwise fp32 -> bf16 convert (row-major), 8 elems/thread/iter.
// ---------------------------------------------------------------------------
__global__ __launch_bounds__(256) void cvt_kernel(
    const float* __restrict__ in, u16* __restrict__ out, int n8)
{
  const int stride = gridDim.x * 256;
  for (int i = blockIdx.x * 256 + threadIdx.x; i < n8; i += stride) {
    union { uint4 u; u16 h[8]; } v;
    load8(in + (long long)i * 8, v.h);
    *(uint4*)(out + (long long)i * 8) = v.u;
  }
}

// ---------------------------------------------------------------------------
// LayerNorm + ReLU over rows of 768 fp32 -> OutT. ReLU propagates NaN.
// ---------------------------------------------------------------------------
template<typename OutT>
__global__ __launch_bounds__(256) void ln_relu_kernel(
    const float* __restrict__ x, const float* __restrict__ g,
    const float* __restrict__ beta, OutT* __restrict__ out)
{
  __shared__ float sa[4], sb[4];
  const float* xr = x + (long long)blockIdx.x * 768;
  float v[3]; float s = 0.f, ss = 0.f;
  #pragma unroll
  for (int j = 0; j < 3; ++j) {
    v[j] = xr[threadIdx.x + j * 256];
    s += v[j]; ss += v[j] * v[j];
  }
  #pragma unroll
  for (int off = 32; off; off >>= 1) {
    s  += __shfl_down(s, off);
    ss += __shfl_down(ss, off);
  }
  const int w = threadIdx.x >> 6, lane = threadIdx.x & 63;
  if (!lane) { sa[w] = s; sb[w] = ss; }
  __syncthreads();
  s  = sa[0] + sa[1] + sa[2] + sa[3];
  ss = sb[0] + sb[1] + sb[2] + sb[3];
  const float mean = s * (1.f / 768.f);
  const float var  = ss * (1.f / 768.f) - mean * mean;
  const float rst  = rsqrtf(var + 1e-5f);
  OutT* orow = out + (long long)blockIdx.x * 768;
  #pragma unroll
  for (int j = 0; j < 3; ++j) {
    const int idx = threadIdx.x + j * 256;
    const float yv = (v[j] - mean) * rst * g[idx] + beta[idx];
    const float rv = (yv <= 0.f) ? 0.f : yv;  // NaN -> yv (propagates)
    orow[idx] = OutT(rv);
  }
}

// ---------------------------------------------------------------------------
// In-place row softmax over 2048 bf16 values (fp32 math)
// ---------------------------------------------------------------------------
__global__ __launch_bounds__(256) void softmax_kernel(u16* __restrict__ sim)
{
  __shared__ float sm[4], ssum[4];
  u16* row = sim + (long long)blockIdx.x * 2048;
  union { uint4 u; u16 h[8]; } v;
  v.u = *(const uint4*)(row + threadIdx.x * 8);
  float f[8]; float mx = -1e30f;
  #pragma unroll
  for (int j = 0; j < 8; ++j) { f[j] = b2f(v.h[j]); mx = fmaxf(mx, f[j]); }
  #pragma unroll
  for (int off = 32; off; off >>= 1) mx = fmaxf(mx, __shfl_down(mx, off));
  const int w = threadIdx.x >> 6, lane = threadIdx.x & 63;
  if (!lane) sm[w] = mx;
  __syncthreads();
  mx = fmaxf(fmaxf(sm[0], sm[1]), fmaxf(sm[2], sm[3]));
  float s = 0.f;
  #pragma unroll
  for (int j = 0; j < 8; ++j) { f[j] = __expf(f[j] - mx); s += f[j]; }
  #pragma unroll
  for (int off = 32; off; off >>= 1) s += __shfl_down(s, off);
  if (!lane) ssum[w] = s;
  __syncthreads();
  s = ssum[0] + ssum[1] + ssum[2] + ssum[3];
  const float inv = 1.f / s;
  #pragma unroll
  for (int j = 0; j < 8; ++j) v.h[j] = f2b(f[j] * inv);
  *(uint4*)(row + threadIdx.x * 8) = v.u;
}

// ---------------------------------------------------------------------------
// claw mean, two deterministic stages
// ---------------------------------------------------------------------------
__global__ __launch_bounds__(256) void claw_partial_kernel(
    const float* __restrict__ claw, float* __restrict__ partial, int n)
{
  __shared__ float sa[4];
  float s = 0.f;
  const int nv = n >> 2;
  for (int i = blockIdx.x * 256 + threadIdx.x; i < nv; i += 64 * 256) {
    float4 v = ((const float4*)claw)[i];
    s += v.x + v.y + v.z + v.w;
  }
  #pragma unroll
  for (int off = 32; off; off >>= 1) s += __shfl_down(s, off);
  const int w = threadIdx.x >> 6, lane = threadIdx.x & 63;
  if (!lane) sa[w] = s;
  __syncthreads();
  if (threadIdx.x == 0)
    partial[blockIdx.x] = sa[0] + sa[1] + sa[2] + sa[3];
}

__global__ void claw_final_kernel(
    const float* __restrict__ partial, float* __restrict__ scale, float inv)
{
  float s = partial[threadIdx.x];
  #pragma unroll
  for (int off = 32; off; off >>= 1) s += __shfl_down(s, off);
  if (threadIdx.x == 0) *scale = s * inv;
}

// ---------------------------------------------------------------------------
extern "C" void kernel_launch(void* const* d_in, const int* in_sizes, int n_in,
                              void* d_out, int out_size, void* d_ws, size_t ws_size,
                              hipStream_t stream)
{
  const float* vis   = (const float*)d_in[0];
  const float* lang  = (const float*)d_in[1];
  const float* vW    = (const float*)d_in[2];
  const float* vb    = (const float*)d_in[3];
  const float* vg    = (const float*)d_in[4];
  const float* vbeta = (const float*)d_in[5];
  const float* lW    = (const float*)d_in[6];
  const float* lb    = (const float*)d_in[7];
  const float* lg    = (const float*)d_in[8];
  const float* lbeta = (const float*)d_in[9];
  const float* claw  = (const float*)d_in[10];
  const float* oW    = (const float*)d_in[11];
  const float* ob    = (const float*)d_in[12];
  const float* og    = (const float*)d_in[13];
  const float* obeta = (const float*)d_in[14];
  float* out = (float*)d_out;

  constexpr int NB = 8, S = 2048, D = 768;
  constexpr int R = NB * S;                       // 16384
  constexpr long long SD = (long long)S * D;      // 1,572,864
  constexpr long long SS = (long long)S * S;      // 4,194,304
  const int nclaw = in_sizes[10];
  const float claw_inv = 1.0f / ((float)nclaw * 0.07f);
  const dim3 blk(256);
  const dim3 blk5(512);

  // Workspace layout (peak 167,772,432 B == proven floor from prior rounds).
  char* ws = (char*)d_ws;
  u16*   vp    = (u16*)  (ws);
  u16*   lp    = (u16*)  (ws + 25165824);
  u16*   visb  = (u16*)  (ws + 50331648);
  u16*   vpT   = (u16*)  (ws + 50331648);
  u16*   langb = (u16*)  (ws + 75497472);
  u16*   lpT   = (u16*)  (ws + 75497472);
  u16*   sim   = (u16*)  (ws + 100663296);
  float* y     = (float*)(ws + 100663296);
  u16*   vWT   = (u16*)  (ws + 150994944);
  u16*   lWT   = vWT + 589824;
  u16*   oWT   = (u16*)  (ws + 150994944);
  u16*   comb  = (u16*)  (ws);
  float* scale   = (float*)(ws + 167772160);
  float* partial = (float*)(ws + 167772176);

  claw_partial_kernel<<<64, blk, 0, stream>>>(claw, partial, nclaw);
  claw_final_kernel<<<1, 64, 0, stream>>>(partial, scale, claw_inv);

  // Weight transposes: W[k][n] fp32 -> WT[n][k] bf16 (direct B operands)
  transpose_kernel<float><<<dim3(12, 12, 1), blk, 0, stream>>>(
      vW, vWT, D, D, 0, 0);
  transpose_kernel<float><<<dim3(12, 12, 1), blk, 0, stream>>>(
      lW, lWT, D, D, 0, 0);

  // vision: visb = bf16(vis); y = visb @ vWT^T + vb; vp = relu(LN(y)); vpT
  cvt_kernel<<<2048, blk, 0, stream>>>(vis, visb, (int)(R * D / 8));
  gemm256<float><<<dim3(D / 256, R / 256, 1), blk5, 0, stream>>>(
      visb, vWT, vb, nullptr, y, D, D, D, D, 0, 0, 0);
  ln_relu_kernel<__hip_bfloat16><<<R, blk, 0, stream>>>(
      y, vg, vbeta, (__hip_bfloat16*)vp);
  transpose_kernel<u16><<<dim3(D / 64, S / 64, NB), blk, 0, stream>>>(
      vp, vpT, S, D, SD, SD);

  // language
  cvt_kernel<<<2048, blk, 0, stream>>>(lang, langb, (int)(R * D / 8));
  gemm256<float><<<dim3(D / 256, R / 256, 1), blk5, 0, stream>>>(
      langb, lWT, lb, nullptr, y, D, D, D, D, 0, 0, 0);
  ln_relu_kernel<__hip_bfloat16><<<R, blk, 0, stream>>>(
      y, lg, lbeta, (__hip_bfloat16*)lp);
  transpose_kernel<u16><<<dim3(D / 64, S / 64, NB), blk, 0, stream>>>(
      lp, lpT, S, D, SD, SD);

  // sim[z] = (vp[z] @ lp[z]^T) * scale
  gemm256<__hip_bfloat16><<<dim3(S / 256, S / 256, NB), blk5, 0, stream>>>(
      vp, lp, nullptr, scale, (__hip_bfloat16*)sim, D, D, D, S, SD, SD, SS);
  softmax_kernel<<<R, blk, 0, stream>>>(sim);

  // aligned_vision[z] = A[z] @ vp[z] -> comb[:, 0:768]  (direct via vpT)
  gemm256<__hip_bfloat16><<<dim3(D / 256, S / 256, NB), blk5, 0, stream>>>(
      sim, vpT, nullptr, nullptr, (__hip_bfloat16*)comb,
      S, S, S, 2 * D, SS, SD, 2 * SD);
  // aligned_language[z] = A[z]^T @ lp[z] -> comb[:, 768:1536]
  // (A scatter over sim; B direct via lpT) - stays on the 128^2 kernel.
  gemm128<1, 0, __hip_bfloat16><<<dim3(D / 128, S / 128, NB), blk, 0, stream>>>(
      sim, lpT, nullptr, nullptr, (__hip_bfloat16*)comb + D,
      S, S, S, 2 * D, SS, SD, 2 * SD);

  // oWT (sim region dead past here except y overlay)
  transpose_kernel<float><<<dim3(12, 24, 1), blk, 0, stream>>>(
      oW, oWT, 2 * D, D, 0, 0);

  // out = relu(LN(comb @ oWT^T + ob))
  gemm256<float><<<dim3(D / 256, R / 256, 1), blk5, 0, stream>>>(
      comb, oWT, ob, nullptr, y, 2 * D, 2 * D, 2 * D, D, 0, 0, 0);
  ln_relu_kernel<float><<<R, blk, 0, stream>>>(y, og, obeta, out);
}

// Round 3
// 620.376 us; speedup vs baseline: 1.0893x; 1.0086x over previous
//
#include <hip/hip_runtime.h>
#include <hip/hip_bf16.h>

typedef short short8 __attribute__((ext_vector_type(8)));
typedef float f32x4 __attribute__((ext_vector_type(4)));
typedef unsigned short u16;

#define BK 32
// Swizzled LDS layout for scatter-staged operands (gemm128 MA==1 path only).
static __device__ __forceinline__ int sw(int row, int g) {
  return row * 32 + ((g ^ ((row >> 3) & 3)) << 3);
}

// fp32 -> bf16 round-to-nearest-even (payload as u16)
static __device__ __forceinline__ u16 f2b(float f) {
  union { float f; unsigned u; } x; x.f = f;
  unsigned r = x.u + 0x7FFF + ((x.u >> 16) & 1);
  return (u16)(r >> 16);
}
static __device__ __forceinline__ float b2f(u16 u) {
  unsigned int x = ((unsigned int)u) << 16;
  float f; __builtin_memcpy(&f, &x, 4);
  return f;
}

static __device__ __forceinline__ void load8(const u16* p, u16* dst) {
  union { uint4 u; u16 h[8]; } t;
  t.u = *(const uint4*)p;
  #pragma unroll
  for (int j = 0; j < 8; ++j) dst[j] = t.h[j];
}
static __device__ __forceinline__ void load8(const float* p, u16* dst) {
  float4 a = ((const float4*)p)[0];
  float4 b = ((const float4*)p)[1];
  dst[0] = f2b(a.x); dst[1] = f2b(a.y); dst[2] = f2b(a.z); dst[3] = f2b(a.w);
  dst[4] = f2b(b.x); dst[5] = f2b(b.y); dst[6] = f2b(b.z); dst[7] = f2b(b.w);
}

// Async global->LDS, 16B per lane (gfx950 global_load_lds_dwordx4).
// LDS dest must be wave-uniform base + lane*16 (m104/m108 caveat).
static __device__ __forceinline__ void gl_lds16(const u16* g, u16* l) {
  __builtin_amdgcn_global_load_lds(
      (const __attribute__((address_space(1))) unsigned int*)g,
      (__attribute__((address_space(3))) unsigned int*)l, 16, 0, 0);
}

// ---------------------------------------------------------------------------
// 256x256x64 8-phase pipelined MFMA GEMM:
//   C[z] = (A[z] @ B[z]^T) * alpha + bias, A:[M][K], B:[N][K], bf16 payloads.
// 512 threads = 8 waves (2M x 4N); per-wave output 128x64 = 8x4 16x16 frags.
// LDS: A,B each 2 x 256x64 bf16 (dbuf) = 128 KiB.
//
// Bank-conflict-free swizzle: row stride = 128B = exact bank wrap, so banks
// depend only on the 16B granule g (0..7). Store element (r, g) at physical
// granule g ^ (r&7): any ds_read_b128 fragment read then spreads its 64
// lanes uniformly 8-per-granule = ideal 8 accesses/bank. gl_lds dest stays
// LINEAR; the inverse permutation is applied to the GLOBAL source column
// (srcg = (tid&7) ^ ((tid>>3)&7)), which keeps wave reads 128B-coalesced.
//
// Phases per K-tile t (16 MFMA each; per-acc order ks0 then ks1, unchanged):
//   P1: rd A mt0-3 ks0 + B ks0 | issue A(t+1,{2,3}), B(t+1,h0) | bar|MFMA|bar
//   P2: rd A mt4-7 ks0         | issue B(t+1,h1)               | bar|MFMA|bar
//   P3: rd A mt0-3 ks1 + B ks1 |                               | bar|MFMA|bar
//   P4: rd A mt4-7 ks1         | issue A(t+2,{0,1})            | bar|MFMA|
//       vmcnt(2) [tail: vmcnt(0)] | bar
// A-chunk c covers rows [32c,32c+32) u [128+32c, ...): chunks {0,1} last read
// in P3, {2,3} in P4 -> A(t+2,{0,1}) may be issued in P4, A(t+2,{2,3}) in the
// NEXT group's P1; B halves are row-halves of the other buffer (safe always).
// Steady state: vmcnt(2) leaves exactly A(t+2,{0,1}) in flight; tile t+1 is
// fully landed before group t+1 reads it.  Requires M,N%256==0, K%64==0.
// ---------------------------------------------------------------------------
template<typename OutT>
__global__ __launch_bounds__(512, 2) void gemm256(
    const u16* __restrict__ A, const u16* __restrict__ B,
    const float* __restrict__ bias, const float* __restrict__ alpha_ptr,
    OutT* __restrict__ C, int K, int lda, int ldb, int ldc,
    long long sA, long long sB, long long sC)
{
  __shared__ u16 As[2][256 * 64];  // 64 KB
  __shared__ u16 Bs[2][256 * 64];  // 64 KB

  A += (long long)blockIdx.z * sA;
  B += (long long)blockIdx.z * sB;
  C += (long long)blockIdx.z * sC;

  const int tid  = threadIdx.x;
  const int m0   = blockIdx.y * 256;
  const int n0   = blockIdx.x * 256;
  const int w    = tid >> 6, lane = tid & 63;
  const int wm   = (w >> 2) * 128;   // 0 / 128
  const int wn   = (w & 3) * 64;     // 0..192
  const int lrow = lane & 15;
  const int lg   = lane >> 4;                     // k-granule 0..3
  const int xa   = lrow & 7;                      // read-side swizzle phase
  const int sr   = tid >> 3;                      // staging row-lane 0..63
  const int srcg = (tid & 7) ^ ((tid >> 3) & 7);  // inverse-swizzled src col
  const int NT   = K >> 6;

  f32x4 acc[8][4] = {};

  // staging: dest is linear (wave-uniform base + lane*16B); source column
  // carries the inverse swizzle so that logical (r,g) lands at g^(r&7).
  auto stA = [&](int t, int c) {
    u16* lb = As[t & 1];
    const int r = (sr < 32) ? (32 * c + sr) : (96 + 32 * c + sr);
    gl_lds16(A + (long long)(m0 + r) * lda + (t * 64 + srcg * 8),
             lb + r * 64 + (tid & 7) * 8);
  };
  auto stB = [&](int t, int h) {
    u16* lb = Bs[t & 1];
    #pragma unroll
    for (int l = 0; l < 2; ++l) {
      const int r = 128 * h + 64 * l + sr;
      gl_lds16(B + (long long)(n0 + r) * ldb + (t * 64 + srcg * 8),
               lb + r * 64 + (tid & 7) * 8);
    }
  };
  auto rdA = [&](int t, int mt, int ks) -> short8 {
    const int r = wm + mt * 16 + lrow;
    return *(const short8*)(As[t & 1] + r * 64 + (((ks * 4 + lg) ^ xa) << 3));
  };
  auto rdB = [&](int t, int nt, int ks) -> short8 {
    const int r = wn + nt * 16 + lrow;
    return *(const short8*)(Bs[t & 1] + r * 64 + (((ks * 4 + lg) ^ xa) << 3));
  };

  // --- prologue: tile0 complete (8 loads) + tile1 A{0,1} in flight ---
  #pragma unroll
  for (int c = 0; c < 4; ++c) stA(0, c);
  stB(0, 0); stB(0, 1);
  if (NT > 1) {
    stA(1, 0); stA(1, 1);
    asm volatile("s_waitcnt vmcnt(2)" ::: "memory");
  } else {
    asm volatile("s_waitcnt vmcnt(0)" ::: "memory");
  }
  __builtin_amdgcn_s_barrier();

  short8 af[4], bfr[4];
  for (int t = 0; t < NT; ++t) {
    // ---- P1: A mt0-3 ks0 + B ks0; issue A(t+1,{2,3}), B(t+1,h0) ----
    #pragma unroll
    for (int i = 0; i < 4; ++i) af[i] = rdA(t, i, 0);
    #pragma unroll
    for (int i = 0; i < 4; ++i) bfr[i] = rdB(t, i, 0);
    if (t + 1 < NT) { stA(t + 1, 2); stA(t + 1, 3); stB(t + 1, 0); }
    __builtin_amdgcn_s_barrier();
    __builtin_amdgcn_s_setprio(1);
    #pragma unroll
    for (int mt = 0; mt < 4; ++mt)
      #pragma unroll
      for (int nt = 0; nt < 4; ++nt)
        acc[mt][nt] = __builtin_amdgcn_mfma_f32_16x16x32_bf16(
            af[mt], bfr[nt], acc[mt][nt], 0, 0, 0);
    __builtin_amdgcn_s_setprio(0);
    __builtin_amdgcn_s_barrier();
    // ---- P2: A mt4-7 ks0; issue B(t+1,h1) ----
    #pragma unroll
    for (int i = 0; i < 4; ++i) af[i] = rdA(t, 4 + i, 0);
    if (t + 1 < NT) stB(t + 1, 1);
    __builtin_amdgcn_s_barrier();
    __builtin_amdgcn_s_setprio(1);
    #pragma unroll
    for (int mt = 0; mt < 4; ++mt)
      #pragma unroll
      for (int nt = 0; nt < 4; ++nt)
        acc[4 + mt][nt] = __builtin_amdgcn_mfma_f32_16x16x32_bf16(
            af[mt], bfr[nt], acc[4 + mt][nt], 0, 0, 0);
    __builtin_amdgcn_s_setprio(0);
    __builtin_amdgcn_s_barrier();
    // ---- P3: A mt0-3 ks1 + B ks1 ----
    #pragma unroll
    for (int i = 0; i < 4; ++i) af[i] = rdA(t, i, 1);
    #pragma unroll
    for (int i = 0; i < 4; ++i) bfr[i] = rdB(t, i, 1);
    __builtin_amdgcn_s_barrier();
    __builtin_amdgcn_s_setprio(1);
    #pragma unroll
    for (int mt = 0; mt < 4; ++mt)
      #pragma unroll
      for (int nt = 0; nt < 4; ++nt)
        acc[mt][nt] = __builtin_amdgcn_mfma_f32_16x16x32_bf16(
            af[mt], bfr[nt], acc[mt][nt], 0, 0, 0);
    __builtin_amdgcn_s_setprio(0);
    __builtin_amdgcn_s_barrier();
    // ---- P4: A mt4-7 ks1; issue A(t+2,{0,1}); counted vmcnt ----
    #pragma unroll
    for (int i = 0; i < 4; ++i) af[i] = rdA(t, 4 + i, 1);
    if (t + 2 < NT) { stA(t + 2, 0); stA(t + 2, 1); }
    __builtin_amdgcn_s_barrier();
    __builtin_amdgcn_s_setprio(1);
    #pragma unroll
    for (int mt = 0; mt < 4; ++mt)
      #pragma unroll
      for (int nt = 0; nt < 4; ++nt)
        acc[4 + mt][nt] = __builtin_amdgcn_mfma_f32_16x16x32_bf16(
            af[mt], bfr[nt], acc[4 + mt][nt], 0, 0, 0);
    __builtin_amdgcn_s_setprio(0);
    if (t + 2 < NT)
      asm volatile("s_waitcnt vmcnt(2)" ::: "memory");
    else
      asm volatile("s_waitcnt vmcnt(0)" ::: "memory");
    __builtin_amdgcn_s_barrier();
  }

  const float alpha = alpha_ptr ? *alpha_ptr : 1.0f;
  #pragma unroll
  for (int nt = 0; nt < 4; ++nt) {
    const int n = n0 + wn + nt * 16 + lrow;
    const float bv = bias ? bias[n] : 0.0f;
    #pragma unroll
    for (int mt = 0; mt < 8; ++mt)
      #pragma unroll
      for (int r = 0; r < 4; ++r) {
        const int m = m0 + wm + mt * 16 + lg * 4 + r;
        C[(long long)m * ldc + n] = OutT(acc[mt][nt][r] * alpha + bv);
      }
  }
}

// ---------------------------------------------------------------------------
// 128x128x32 MFMA GEMM (m97 structure), kept for the A^T scatter case only.
//   MA==1: A is k-strided [K][M] (sim columns); swizzled scalar LDS scatter.
//   MB==0: B direct bf16 [N][K] via global_load_lds.
// ---------------------------------------------------------------------------
template<int MA, int MB, typename OutT>
__global__ __launch_bounds__(256) void gemm128(
    const u16* __restrict__ A, const u16* __restrict__ B,
    const float* __restrict__ bias, const float* __restrict__ alpha_ptr,
    OutT* __restrict__ C, int K, int lda, int ldb, int ldc,
    long long sA, long long sB, long long sC)
{
  __shared__ u16 As[128 * 32];
  __shared__ u16 Bs[128 * 32];

  A += (long long)blockIdx.z * sA;
  B += (long long)blockIdx.z * sB;
  C += (long long)blockIdx.z * sC;

  const int tid  = threadIdx.x;
  const int m0   = blockIdx.y * 128;
  const int n0   = blockIdx.x * 128;
  const int w    = tid >> 6, lane = tid & 63;
  const int wm   = (w >> 1) * 64;
  const int wn   = (w & 1) * 64;
  const int lrow = lane & 15;
  const int lg   = lane >> 4;

  int aoff[4], boff[4];
  #pragma unroll
  for (int t = 0; t < 4; ++t) {
    const int ar = wm + t * 16 + lrow;
    const int br = wn + t * 16 + lrow;
    aoff[t] = (MA == 1) ? sw(ar, lg) : ar * 32 + lg * 8;
    boff[t] = (MB == 1) ? sw(br, lg) : br * 32 + lg * 8;
  }

  f32x4 acc[4][4] = {};

  for (int k0 = 0; k0 < K; k0 += BK) {
    if constexpr (MA == 0) {
      gl_lds16(A + (long long)(m0 + (tid >> 2)) * lda + (k0 + (tid & 3) * 8),
               As + tid * 8);
      gl_lds16(A + (long long)(m0 + 64 + (tid >> 2)) * lda + (k0 + (tid & 3) * 8),
               As + 2048 + tid * 8);
    } else {
      const int kk = tid >> 3;
      #pragma unroll
      for (int p = 0; p < 2; ++p) {
        const int rr = (tid & 7) * 8 + p * 64;
        u16 h[8];
        load8(A + (long long)(k0 + kk) * lda + (m0 + rr), h);
        #pragma unroll
        for (int j = 0; j < 8; ++j) As[sw(rr + j, kk >> 3) + (kk & 7)] = h[j];
      }
    }
    if constexpr (MB == 0) {
      gl_lds16(B + (long long)(n0 + (tid >> 2)) * ldb + (k0 + (tid & 3) * 8),
               Bs + tid * 8);
      gl_lds16(B + (long long)(n0 + 64 + (tid >> 2)) * ldb + (k0 + (tid & 3) * 8),
               Bs + 2048 + tid * 8);
    } else {
      const int kk = tid >> 3;
      #pragma unroll
      for (int p = 0; p < 2; ++p) {
        const int rr = (tid & 7) * 8 + p * 64;
        u16 h[8];
        load8(B + (long long)(k0 + kk) * ldb + (n0 + rr), h);
        #pragma unroll
        for (int j = 0; j < 8; ++j) Bs[sw(rr + j, kk >> 3) + (kk & 7)] = h[j];
      }
    }
    __syncthreads();

    short8 af[4], bf[4];
    #pragma unroll
    for (int t = 0; t < 4; ++t) af[t] = *(const short8*)(As + aoff[t]);
    #pragma unroll
    for (int t = 0; t < 4; ++t) bf[t] = *(const short8*)(Bs + boff[t]);
    #pragma unroll
    for (int mt = 0; mt < 4; ++mt)
      #pragma unroll
      for (int nt = 0; nt < 4; ++nt)
        acc[mt][nt] = __builtin_amdgcn_mfma_f32_16x16x32_bf16(
            af[mt], bf[nt], acc[mt][nt], 0, 0, 0);
    __syncthreads();
  }

  const float alpha = alpha_ptr ? *alpha_ptr : 1.0f;
  #pragma unroll
  for (int nt = 0; nt < 4; ++nt) {
    const int n = n0 + wn + nt * 16 + lrow;
    const float bv = bias ? bias[n] : 0.0f;
    #pragma unroll
    for (int mt = 0; mt < 4; ++mt) {
      #pragma unroll
      for (int r = 0; r < 4; ++r) {
        const int m = m0 + wm + mt * 16 + lg * 4 + r;
        C[(long long)m * ldc + n] = OutT(acc[mt][nt][r] * alpha + bv);
      }
    }
  }
}

// ---------------------------------------------------------------------------
// Tiled 64x64 transpose with optional fp32->bf16 convert.
// ---------------------------------------------------------------------------
template<typename T>
__global__ __launch_bounds__(256) void transpose_kernel(
    const T* __restrict__ in, u16* __restrict__ out, int R, int C,
    long long sIn, long long sOut)
{
  __shared__ u16 t[64][66];
  in  += (long long)blockIdx.z * sIn;
  out += (long long)blockIdx.z * sOut;
  const int r0 = blockIdx.y * 64, c0 = blockIdx.x * 64;
  const int tid = threadIdx.x;
  const int rr = tid >> 3, cc = (tid & 7) * 8;
  #pragma unroll
  for (int p = 0; p < 2; ++p) {
    union { uint4 u; unsigned w[4]; u16 h[8]; } v;
    const int row = rr + p * 32;
    load8(in + (long long)(r0 + row) * C + (c0 + cc), v.h);
    #pragma unroll
    for (int k = 0; k < 4; ++k)
      *(unsigned*)&t[row][cc + k * 2] = v.w[k];
  }
  __syncthreads();
  #pragma unroll
  for (int p = 0; p < 2; ++p) {
    const int oc = (tid >> 3) + p * 32;
    const int rc = (tid & 7) * 8;
    union { uint4 u; u16 h[8]; } g;
    #pragma unroll
    for (int j = 0; j < 8; ++j) g.h[j] = t[rc + j][oc];
    *(uint4*)(out + (long long)(c0 + oc) * R + (r0 + rc)) = g.u;
  }
}

// ---------------------------------------------------------------------------
// Elementwise fp32 -> bf16 convert (row-major), 8 elems/thread/iter.
// ---------------------------------------------------------------------------
__global__ __launch_bounds__(256) void cvt_kernel(
    const float* __restrict__ in, u16* __restrict__ out, int n8)
{
  const int stride = gridDim.x * 256;
  for (int i = blockIdx.x * 256 + threadIdx.x; i < n8; i += stride) {
    union { uint4 u; u16 h[8]; } v;
    load8(in + (long long)i * 8, v.h);
    *(uint4*)(out + (long long)i * 8) = v.u;
  }
}

// ---------------------------------------------------------------------------
// LayerNorm + ReLU over rows of 768 fp32 -> OutT. ReLU propagates NaN.
// ---------------------------------------------------------------------------
template<typename OutT>
__global__ __launch_bounds__(256) void ln_relu_kernel(
    const float* __restrict__ x, const float* __restrict__ g,
    const float* __restrict__ beta, OutT* __restrict__ out)
{
  __shared__ float sa[4], sb[4];
  const float* xr = x + (long long)blockIdx.x * 768;
  float v[3]; float s = 0.f, ss = 0.f;
  #pragma unroll
  for (int j = 0; j < 3; ++j) {
    v[j] = xr[threadIdx.x + j * 256];
    s += v[j]; ss += v[j] * v[j];
  }
  #pragma unroll
  for (int off = 32; off; off >>= 1) {
    s  += __shfl_down(s, off);
    ss += __shfl_down(ss, off);
  }
  const int w = threadIdx.x >> 6, lane = threadIdx.x & 63;
  if (!lane) { sa[w] = s; sb[w] = ss; }
  __syncthreads();
  s  = sa[0] + sa[1] + sa[2] + sa[3];
  ss = sb[0] + sb[1] + sb[2] + sb[3];
  const float mean = s * (1.f / 768.f);
  const float var  = ss * (1.f / 768.f) - mean * mean;
  const float rst  = rsqrtf(var + 1e-5f);
  OutT* orow = out + (long long)blockIdx.x * 768;
  #pragma unroll
  for (int j = 0; j < 3; ++j) {
    const int idx = threadIdx.x + j * 256;
    const float yv = (v[j] - mean) * rst * g[idx] + beta[idx];
    const float rv = (yv <= 0.f) ? 0.f : yv;  // NaN -> yv (propagates)
    orow[idx] = OutT(rv);
  }
}

// ---------------------------------------------------------------------------
// In-place row softmax over 2048 bf16 values (fp32 math)
// ---------------------------------------------------------------------------
__global__ __launch_bounds__(256) void softmax_kernel(u16* __restrict__ sim)
{
  __shared__ float sm[4], ssum[4];
  u16* row = sim + (long long)blockIdx.x * 2048;
  union { uint4 u; u16 h[8]; } v;
  v.u = *(const uint4*)(row + threadIdx.x * 8);
  float f[8]; float mx = -1e30f;
  #pragma unroll
  for (int j = 0; j < 8; ++j) { f[j] = b2f(v.h[j]); mx = fmaxf(mx, f[j]); }
  #pragma unroll
  for (int off = 32; off; off >>= 1) mx = fmaxf(mx, __shfl_down(mx, off));
  const int w = threadIdx.x >> 6, lane = threadIdx.x & 63;
  if (!lane) sm[w] = mx;
  __syncthreads();
  mx = fmaxf(fmaxf(sm[0], sm[1]), fmaxf(sm[2], sm[3]));
  float s = 0.f;
  #pragma unroll
  for (int j = 0; j < 8; ++j) { f[j] = __expf(f[j] - mx); s += f[j]; }
  #pragma unroll
  for (int off = 32; off; off >>= 1) s += __shfl_down(s, off);
  if (!lane) ssum[w] = s;
  __syncthreads();
  s = ssum[0] + ssum[1] + ssum[2] + ssum[3];
  const float inv = 1.f / s;
  #pragma unroll
  for (int j = 0; j < 8; ++j) v.h[j] = f2b(f[j] * inv);
  *(uint4*)(row + threadIdx.x * 8) = v.u;
}

// ---------------------------------------------------------------------------
// claw mean, two deterministic stages
// ---------------------------------------------------------------------------
__global__ __launch_bounds__(256) void claw_partial_kernel(
    const float* __restrict__ claw, float* __restrict__ partial, int n)
{
  __shared__ float sa[4];
  float s = 0.f;
  const int nv = n >> 2;
  for (int i = blockIdx.x * 256 + threadIdx.x; i < nv; i += 64 * 256) {
    float4 v = ((const float4*)claw)[i];
    s += v.x + v.y + v.z + v.w;
  }
  #pragma unroll
  for (int off = 32; off; off >>= 1) s += __shfl_down(s, off);
  const int w = threadIdx.x >> 6, lane = threadIdx.x & 63;
  if (!lane) sa[w] = s;
  __syncthreads();
  if (threadIdx.x == 0)
    partial[blockIdx.x] = sa[0] + sa[1] + sa[2] + sa[3];
}

__global__ void claw_final_kernel(
    const float* __restrict__ partial, float* __restrict__ scale, float inv)
{
  float s = partial[threadIdx.x];
  #pragma unroll
  for (int off = 32; off; off >>= 1) s += __shfl_down(s, off);
  if (threadIdx.x == 0) *scale = s * inv;
}

// ---------------------------------------------------------------------------
extern "C" void kernel_launch(void* const* d_in, const int* in_sizes, int n_in,
                              void* d_out, int out_size, void* d_ws, size_t ws_size,
                              hipStream_t stream)
{
  const float* vis   = (const float*)d_in[0];
  const float* lang  = (const float*)d_in[1];
  const float* vW    = (const float*)d_in[2];
  const float* vb    = (const float*)d_in[3];
  const float* vg    = (const float*)d_in[4];
  const float* vbeta = (const float*)d_in[5];
  const float* lW    = (const float*)d_in[6];
  const float* lb    = (const float*)d_in[7];
  const float* lg    = (const float*)d_in[8];
  const float* lbeta = (const float*)d_in[9];
  const float* claw  = (const float*)d_in[10];
  const float* oW    = (const float*)d_in[11];
  const float* ob    = (const float*)d_in[12];
  const float* og    = (const float*)d_in[13];
  const float* obeta = (const float*)d_in[14];
  float* out = (float*)d_out;

  constexpr int NB = 8, S = 2048, D = 768;
  constexpr int R = NB * S;                       // 16384
  constexpr long long SD = (long long)S * D;      // 1,572,864
  constexpr long long SS = (long long)S * S;      // 4,194,304
  const int nclaw = in_sizes[10];
  const float claw_inv = 1.0f / ((float)nclaw * 0.07f);
  const dim3 blk(256);
  const dim3 blk5(512);

  // Workspace layout (peak 167,772,432 B == proven floor from prior rounds).
  char* ws = (char*)d_ws;
  u16*   vp    = (u16*)  (ws);
  u16*   lp    = (u16*)  (ws + 25165824);
  u16*   visb  = (u16*)  (ws + 50331648);
  u16*   vpT   = (u16*)  (ws + 50331648);
  u16*   langb = (u16*)  (ws + 75497472);
  u16*   lpT   = (u16*)  (ws + 75497472);
  u16*   sim   = (u16*)  (ws + 100663296);
  float* y     = (float*)(ws + 100663296);
  u16*   vWT   = (u16*)  (ws + 150994944);
  u16*   lWT   = vWT + 589824;
  u16*   oWT   = (u16*)  (ws + 150994944);
  u16*   comb  = (u16*)  (ws);
  float* scale   = (float*)(ws + 167772160);
  float* partial = (float*)(ws + 167772176);

  claw_partial_kernel<<<64, blk, 0, stream>>>(claw, partial, nclaw);
  claw_final_kernel<<<1, 64, 0, stream>>>(partial, scale, claw_inv);

  // Weight transposes: W[k][n] fp32 -> WT[n][k] bf16 (direct B operands)
  transpose_kernel<float><<<dim3(12, 12, 1), blk, 0, stream>>>(
      vW, vWT, D, D, 0, 0);
  transpose_kernel<float><<<dim3(12, 12, 1), blk, 0, stream>>>(
      lW, lWT, D, D, 0, 0);

  // vision: visb = bf16(vis); y = visb @ vWT^T + vb; vp = relu(LN(y)); vpT
  cvt_kernel<<<2048, blk, 0, stream>>>(vis, visb, (int)(R * D / 8));
  gemm256<float><<<dim3(D / 256, R / 256, 1), blk5, 0, stream>>>(
      visb, vWT, vb, nullptr, y, D, D, D, D, 0, 0, 0);
  ln_relu_kernel<__hip_bfloat16><<<R, blk, 0, stream>>>(
      y, vg, vbeta, (__hip_bfloat16*)vp);
  transpose_kernel<u16><<<dim3(D / 64, S / 64, NB), blk, 0, stream>>>(
      vp, vpT, S, D, SD, SD);

  // language
  cvt_kernel<<<2048, blk, 0, stream>>>(lang, langb, (int)(R * D / 8));
  gemm256<float><<<dim3(D / 256, R / 256, 1), blk5, 0, stream>>>(
      langb, lWT, lb, nullptr, y, D, D, D, D, 0, 0, 0);
  ln_relu_kernel<__hip_bfloat16><<<R, blk, 0, stream>>>(
      y, lg, lbeta, (__hip_bfloat16*)lp);
  transpose_kernel<u16><<<dim3(D / 64, S / 64, NB), blk, 0, stream>>>(
      lp, lpT, S, D, SD, SD);

  // sim[z] = (vp[z] @ lp[z]^T) * scale
  gemm256<__hip_bfloat16><<<dim3(S / 256, S / 256, NB), blk5, 0, stream>>>(
      vp, lp, nullptr, scale, (__hip_bfloat16*)sim, D, D, D, S, SD, SD, SS);
  softmax_kernel<<<R, blk, 0, stream>>>(sim);

  // aligned_vision[z] = A[z] @ vp[z] -> comb[:, 0:768]  (direct via vpT)
  gemm256<__hip_bfloat16><<<dim3(D / 256, S / 256, NB), blk5, 0, stream>>>(
      sim, vpT, nullptr, nullptr, (__hip_bfloat16*)comb,
      S, S, S, 2 * D, SS, SD, 2 * SD);
  // aligned_language[z] = A[z]^T @ lp[z] -> comb[:, 768:1536]
  // (A scatter over sim; B direct via lpT) - stays on the 128^2 kernel.
  gemm128<1, 0, __hip_bfloat16><<<dim3(D / 128, S / 128, NB), blk, 0, stream>>>(
      sim, lpT, nullptr, nullptr, (__hip_bfloat16*)comb + D,
      S, S, S, 2 * D, SS, SD, 2 * SD);

  // oWT (sim region dead past here except y overlay)
  transpose_kernel<float><<<dim3(12, 24, 1), blk, 0, stream>>>(
      oW, oWT, 2 * D, D, 0, 0);

  // out = relu(LN(comb @ oWT^T + ob))
  gemm256<float><<<dim3(D / 256, R / 256, 1), blk5, 0, stream>>>(
      comb, oWT, ob, nullptr, y, 2 * D, 2 * D, 2 * D, D, 0, 0, 0);
  ln_relu_kernel<float><<<R, blk, 0, stream>>>(y, og, obeta, out);
}

// Round 5
// 593.873 us; speedup vs baseline: 1.1379x; 1.0446x over previous
//
#include <hip/hip_runtime.h>
#include <hip/hip_bf16.h>

typedef short short8 __attribute__((ext_vector_type(8)));
typedef float f32x4 __attribute__((ext_vector_type(4)));
typedef unsigned short u16;

#define BK 32
// Swizzled LDS layout for scatter-staged operands (gemm128 MA==1 path only).
static __device__ __forceinline__ int sw(int row, int g) {
  return row * 32 + ((g ^ ((row >> 3) & 3)) << 3);
}

// fp32 -> bf16 round-to-nearest-even (payload as u16)
static __device__ __forceinline__ u16 f2b(float f) {
  union { float f; unsigned u; } x; x.f = f;
  unsigned r = x.u + 0x7FFF + ((x.u >> 16) & 1);
  return (u16)(r >> 16);
}
static __device__ __forceinline__ float b2f(u16 u) {
  unsigned int x = ((unsigned int)u) << 16;
  float f; __builtin_memcpy(&f, &x, 4);
  return f;
}

static __device__ __forceinline__ void load8(const u16* p, u16* dst) {
  union { uint4 u; u16 h[8]; } t;
  t.u = *(const uint4*)p;
  #pragma unroll
  for (int j = 0; j < 8; ++j) dst[j] = t.h[j];
}
static __device__ __forceinline__ void load8(const float* p, u16* dst) {
  float4 a = ((const float4*)p)[0];
  float4 b = ((const float4*)p)[1];
  dst[0] = f2b(a.x); dst[1] = f2b(a.y); dst[2] = f2b(a.z); dst[3] = f2b(a.w);
  dst[4] = f2b(b.x); dst[5] = f2b(b.y); dst[6] = f2b(b.z); dst[7] = f2b(b.w);
}

// Async global->LDS, 16B per lane (gfx950 global_load_lds_dwordx4).
// LDS dest must be wave-uniform base + lane*16 (m104/m108 caveat).
static __device__ __forceinline__ void gl_lds16(const u16* g, u16* l) {
  __builtin_amdgcn_global_load_lds(
      (const __attribute__((address_space(1))) unsigned int*)g,
      (__attribute__((address_space(3))) unsigned int*)l, 16, 0, 0);
}

// Inline-asm ds_read_b128: opaque to SIInsertWaitcnts, so the LDS-DMA
// (global_load_lds) alias tracking cannot force a vmcnt(0) drain before it.
// "=&v" early-clobber: guarantee the address VGPR is not allocated inside
// the destination quad. Caller is responsible for s_waitcnt lgkmcnt(0) +
// sched_barrier(0) before consuming the result (rule 18).
template<int OFF>
static __device__ __forceinline__ short8 dsr128(unsigned addr) {
  short8 d;
  asm volatile("ds_read_b128 %0, %1 offset:%2"
               : "=&v"(d) : "v"(addr), "n"(OFF));
  return d;
}
// 32-bit LDS byte offset of a __shared__ pointer (addrspacecast to AS3).
static __device__ __forceinline__ unsigned lds_off(const u16* p) {
  return (unsigned)(unsigned long long)
      (const __attribute__((address_space(3))) u16*)p;
}

// ---------------------------------------------------------------------------
// 256x256x64 8-phase pipelined MFMA GEMM:
//   C[z] = (A[z] @ B[z]^T) * alpha + bias, A:[M][K], B:[N][K], bf16 payloads.
// 512 threads = 8 waves (2M x 4N); per-wave output 128x64 = 8x4 16x16 frags.
// LDS: A,B each 2 x 256x64 bf16 (dbuf) = 128 KiB.
//
// Swizzle: row stride = 128B = exact bank wrap, so banks depend only on the
// 16B granule g (0..7). Element (r,g) stored at granule g^(r&7): uniform
// 8 lanes/granule on every ds_read_b128. gl_lds dest stays LINEAR; inverse
// permutation applied to the GLOBAL source column (srcg), reads swizzled.
//
// Fragment loads are inline-asm ds_read_b128 (see dsr128): plain C++ LDS
// reads aliasing the global_load_lds destination made the compiler insert
// vmcnt(0) drains every phase (observed R2/R3: 8-phase ran at 2-phase speed,
// T4 defeated). Explicit lgkmcnt(0)+sched_barrier(0) precedes each MFMA
// cluster; counted vmcnt(2) once per K-tile is the ONLY vmem wait.
//
// Phases per K-tile t (16 MFMA each; per-acc order ks0 then ks1):
//   P1: rd A mt0-3 ks0 + B ks0 | issue A(t+1,{2,3}), B(t+1,h0) | bar|MFMA|bar
//   P2: rd A mt4-7 ks0         | issue B(t+1,h1)               | bar|MFMA|bar
//   P3: rd A mt0-3 ks1 + B ks1 |                               | bar|MFMA|bar
//   P4: rd A mt4-7 ks1         | issue A(t+2,{0,1})            | bar|MFMA|
//       vmcnt(2) [tail: vmcnt(0)] | bar
// WAR ledger: stA(t+2,{0,1}) writes buf[t&1] rows [0,64)u[128,192); those
// rows' last reads (P3 mt0-3 / disjoint in P4) are lgkmcnt(0)-complete
// before P3's trailing barrier, which precedes the issue. Steady state:
// vmcnt(2) leaves exactly A(t+2,{0,1}) in flight; tile t+1 fully landed
// before group t+1 reads it.  Requires M,N%256==0, K%64==0.
// ---------------------------------------------------------------------------
template<typename OutT>
__global__ __launch_bounds__(512, 2) void gemm256(
    const u16* __restrict__ A, const u16* __restrict__ B,
    const float* __restrict__ bias, const float* __restrict__ alpha_ptr,
    OutT* __restrict__ C, int K, int lda, int ldb, int ldc,
    long long sA, long long sB, long long sC)
{
  __shared__ u16 As[2][256 * 64];  // 64 KB
  __shared__ u16 Bs[2][256 * 64];  // 64 KB

  A += (long long)blockIdx.z * sA;
  B += (long long)blockIdx.z * sB;
  C += (long long)blockIdx.z * sC;

  const int tid  = threadIdx.x;
  const int m0   = blockIdx.y * 256;
  const int n0   = blockIdx.x * 256;
  const int w    = tid >> 6, lane = tid & 63;
  const int wm   = (w >> 2) * 128;   // 0 / 128
  const int wn   = (w & 3) * 64;     // 0..192
  const int lrow = lane & 15;
  const int lg   = lane >> 4;                     // k-granule 0..3
  const int xa   = lrow & 7;                      // read-side swizzle phase
  const int sr   = tid >> 3;                      // staging row-lane 0..63
  const int srcg = (tid & 7) ^ ((tid >> 3) & 7);  // inverse-swizzled src col
  const int NT   = K >> 6;

  f32x4 acc[8][4] = {};

  // staging: dest is linear (wave-uniform base + lane*16B); source column
  // carries the inverse swizzle so that logical (r,g) lands at g^(r&7).
  auto stA = [&](int t, int c) {
    u16* lb = As[t & 1];
    const int r = (sr < 32) ? (32 * c + sr) : (96 + 32 * c + sr);
    gl_lds16(A + (long long)(m0 + r) * lda + (t * 64 + srcg * 8),
             lb + r * 64 + (tid & 7) * 8);
  };
  auto stB = [&](int t, int h) {
    u16* lb = Bs[t & 1];
    #pragma unroll
    for (int l = 0; l < 2; ++l) {
      const int r = 128 * h + 64 * l + sr;
      gl_lds16(B + (long long)(n0 + r) * ldb + (t * 64 + srcg * 8),
               lb + r * 64 + (tid & 7) * 8);
    }
  };

  // Precomputed 32-bit LDS read addresses (buf0; buf1 = +32768 B).
  // row*128B + swizzled-granule*16B; mt/nt sub-tiles via offset: mt*2048.
  const unsigned aRow = lds_off(&As[0][0]) + (wm + lrow) * 128;
  const unsigned bRow = lds_off(&Bs[0][0]) + (wn + lrow) * 128;
  const unsigned gk0  = (unsigned)((lg ^ xa) << 4);
  const unsigned gk1  = (unsigned)(((4 + lg) ^ xa) << 4);

  // --- prologue: tile0 complete (8 loads) + tile1 A{0,1} in flight ---
  #pragma unroll
  for (int c = 0; c < 4; ++c) stA(0, c);
  stB(0, 0); stB(0, 1);
  if (NT > 1) {
    stA(1, 0); stA(1, 1);
    asm volatile("s_waitcnt vmcnt(2)" ::: "memory");
  } else {
    asm volatile("s_waitcnt vmcnt(0)" ::: "memory");
  }
  __builtin_amdgcn_s_barrier();

  short8 af[4], bfr[4];
  for (int t = 0; t < NT; ++t) {
    const unsigned ab = aRow + ((t & 1) << 15);
    const unsigned bb = bRow + ((t & 1) << 15);
    const unsigned a0 = ab + gk0, a1 = ab + gk1;
    const unsigned b0 = bb + gk0, b1 = bb + gk1;
    // ---- P1: A mt0-3 ks0 + B ks0; issue A(t+1,{2,3}), B(t+1,h0) ----
    af[0] = dsr128<0>(a0);    af[1] = dsr128<2048>(a0);
    af[2] = dsr128<4096>(a0); af[3] = dsr128<6144>(a0);
    bfr[0] = dsr128<0>(b0);    bfr[1] = dsr128<2048>(b0);
    bfr[2] = dsr128<4096>(b0); bfr[3] = dsr128<6144>(b0);
    if (t + 1 < NT) { stA(t + 1, 2); stA(t + 1, 3); stB(t + 1, 0); }
    __builtin_amdgcn_s_barrier();
    asm volatile("s_waitcnt lgkmcnt(0)");
    __builtin_amdgcn_sched_barrier(0);
    __builtin_amdgcn_s_setprio(1);
    #pragma unroll
    for (int mt = 0; mt < 4; ++mt)
      #pragma unroll
      for (int nt = 0; nt < 4; ++nt)
        acc[mt][nt] = __builtin_amdgcn_mfma_f32_16x16x32_bf16(
            af[mt], bfr[nt], acc[mt][nt], 0, 0, 0);
    __builtin_amdgcn_s_setprio(0);
    __builtin_amdgcn_s_barrier();
    // ---- P2: A mt4-7 ks0; issue B(t+1,h1) ----
    af[0] = dsr128<8192>(a0);  af[1] = dsr128<10240>(a0);
    af[2] = dsr128<12288>(a0); af[3] = dsr128<14336>(a0);
    if (t + 1 < NT) stB(t + 1, 1);
    __builtin_amdgcn_s_barrier();
    asm volatile("s_waitcnt lgkmcnt(0)");
    __builtin_amdgcn_sched_barrier(0);
    __builtin_amdgcn_s_setprio(1);
    #pragma unroll
    for (int mt = 0; mt < 4; ++mt)
      #pragma unroll
      for (int nt = 0; nt < 4; ++nt)
        acc[4 + mt][nt] = __builtin_amdgcn_mfma_f32_16x16x32_bf16(
            af[mt], bfr[nt], acc[4 + mt][nt], 0, 0, 0);
    __builtin_amdgcn_s_setprio(0);
    __builtin_amdgcn_s_barrier();
    // ---- P3: A mt0-3 ks1 + B ks1 ----
    af[0] = dsr128<0>(a1);    af[1] = dsr128<2048>(a1);
    af[2] = dsr128<4096>(a1); af[3] = dsr128<6144>(a1);
    bfr[0] = dsr128<0>(b1);    bfr[1] = dsr128<2048>(b1);
    bfr[2] = dsr128<4096>(b1); bfr[3] = dsr128<6144>(b1);
    __builtin_amdgcn_s_barrier();
    asm volatile("s_waitcnt lgkmcnt(0)");
    __builtin_amdgcn_sched_barrier(0);
    __builtin_amdgcn_s_setprio(1);
    #pragma unroll
    for (int mt = 0; mt < 4; ++mt)
      #pragma unroll
      for (int nt = 0; nt < 4; ++nt)
        acc[mt][nt] = __builtin_amdgcn_mfma_f32_16x16x32_bf16(
            af[mt], bfr[nt], acc[mt][nt], 0, 0, 0);
    __builtin_amdgcn_s_setprio(0);
    __builtin_amdgcn_s_barrier();
    // ---- P4: A mt4-7 ks1; issue A(t+2,{0,1}); counted vmcnt ----
    af[0] = dsr128<8192>(a1);  af[1] = dsr128<10240>(a1);
    af[2] = dsr128<12288>(a1); af[3] = dsr128<14336>(a1);
    if (t + 2 < NT) { stA(t + 2, 0); stA(t + 2, 1); }
    __builtin_amdgcn_s_barrier();
    asm volatile("s_waitcnt lgkmcnt(0)");
    __builtin_amdgcn_sched_barrier(0);
    __builtin_amdgcn_s_setprio(1);
    #pragma unroll
    for (int mt = 0; mt < 4; ++mt)
      #pragma unroll
      for (int nt = 0; nt < 4; ++nt)
        acc[4 + mt][nt] = __builtin_amdgcn_mfma_f32_16x16x32_bf16(
            af[mt], bfr[nt], acc[4 + mt][nt], 0, 0, 0);
    __builtin_amdgcn_s_setprio(0);
    if (t + 2 < NT)
      asm volatile("s_waitcnt vmcnt(2)" ::: "memory");
    else
      asm volatile("s_waitcnt vmcnt(0)" ::: "memory");
    __builtin_amdgcn_s_barrier();
  }

  const float alpha = alpha_ptr ? *alpha_ptr : 1.0f;
  #pragma unroll
  for (int nt = 0; nt < 4; ++nt) {
    const int n = n0 + wn + nt * 16 + lrow;
    const float bv = bias ? bias[n] : 0.0f;
    #pragma unroll
    for (int mt = 0; mt < 8; ++mt)
      #pragma unroll
      for (int r = 0; r < 4; ++r) {
        const int m = m0 + wm + mt * 16 + lg * 4 + r;
        C[(long long)m * ldc + n] = OutT(acc[mt][nt][r] * alpha + bv);
      }
  }
}

// ---------------------------------------------------------------------------
// 128x128x32 MFMA GEMM (m97 structure), kept for the A^T scatter case only.
//   MA==1: A is k-strided [K][M] (sim columns); swizzled scalar LDS scatter.
//   MB==0: B direct bf16 [N][K] via global_load_lds.
// ---------------------------------------------------------------------------
template<int MA, int MB, typename OutT>
__global__ __launch_bounds__(256) void gemm128(
    const u16* __restrict__ A, const u16* __restrict__ B,
    const float* __restrict__ bias, const float* __restrict__ alpha_ptr,
    OutT* __restrict__ C, int K, int lda, int ldb, int ldc,
    long long sA, long long sB, long long sC)
{
  __shared__ u16 As[128 * 32];
  __shared__ u16 Bs[128 * 32];

  A += (long long)blockIdx.z * sA;
  B += (long long)blockIdx.z * sB;
  C += (long long)blockIdx.z * sC;

  const int tid  = threadIdx.x;
  const int m0   = blockIdx.y * 128;
  const int n0   = blockIdx.x * 128;
  const int w    = tid >> 6, lane = tid & 63;
  const int wm   = (w >> 1) * 64;
  const int wn   = (w & 1) * 64;
  const int lrow = lane & 15;
  const int lg   = lane >> 4;

  int aoff[4], boff[4];
  #pragma unroll
  for (int t = 0; t < 4; ++t) {
    const int ar = wm + t * 16 + lrow;
    const int br = wn + t * 16 + lrow;
    aoff[t] = (MA == 1) ? sw(ar, lg) : ar * 32 + lg * 8;
    boff[t] = (MB == 1) ? sw(br, lg) : br * 32 + lg * 8;
  }

  f32x4 acc[4][4] = {};

  for (int k0 = 0; k0 < K; k0 += BK) {
    if constexpr (MA == 0) {
      gl_lds16(A + (long long)(m0 + (tid >> 2)) * lda + (k0 + (tid & 3) * 8),
               As + tid * 8);
      gl_lds16(A + (long long)(m0 + 64 + (tid >> 2)) * lda + (k0 + (tid & 3) * 8),
               As + 2048 + tid * 8);
    } else {
      const int kk = tid >> 3;
      #pragma unroll
      for (int p = 0; p < 2; ++p) {
        const int rr = (tid & 7) * 8 + p * 64;
        u16 h[8];
        load8(A + (long long)(k0 + kk) * lda + (m0 + rr), h);
        #pragma unroll
        for (int j = 0; j < 8; ++j) As[sw(rr + j, kk >> 3) + (kk & 7)] = h[j];
      }
    }
    if constexpr (MB == 0) {
      gl_lds16(B + (long long)(n0 + (tid >> 2)) * ldb + (k0 + (tid & 3) * 8),
               Bs + tid * 8);
      gl_lds16(B + (long long)(n0 + 64 + (tid >> 2)) * ldb + (k0 + (tid & 3) * 8),
               Bs + 2048 + tid * 8);
    } else {
      const int kk = tid >> 3;
      #pragma unroll
      for (int p = 0; p < 2; ++p) {
        const int rr = (tid & 7) * 8 + p * 64;
        u16 h[8];
        load8(B + (long long)(k0 + kk) * ldb + (n0 + rr), h);
        #pragma unroll
        for (int j = 0; j < 8; ++j) Bs[sw(rr + j, kk >> 3) + (kk & 7)] = h[j];
      }
    }
    __syncthreads();

    short8 af[4], bf[4];
    #pragma unroll
    for (int t = 0; t < 4; ++t) af[t] = *(const short8*)(As + aoff[t]);
    #pragma unroll
    for (int t = 0; t < 4; ++t) bf[t] = *(const short8*)(Bs + boff[t]);
    #pragma unroll
    for (int mt = 0; mt < 4; ++mt)
      #pragma unroll
      for (int nt = 0; nt < 4; ++nt)
        acc[mt][nt] = __builtin_amdgcn_mfma_f32_16x16x32_bf16(
            af[mt], bf[nt], acc[mt][nt], 0, 0, 0);
    __syncthreads();
  }

  const float alpha = alpha_ptr ? *alpha_ptr : 1.0f;
  #pragma unroll
  for (int nt = 0; nt < 4; ++nt) {
    const int n = n0 + wn + nt * 16 + lrow;
    const float bv = bias ? bias[n] : 0.0f;
    #pragma unroll
    for (int mt = 0; mt < 4; ++mt) {
      #pragma unroll
      for (int r = 0; r < 4; ++r) {
        const int m = m0 + wm + mt * 16 + lg * 4 + r;
        C[(long long)m * ldc + n] = OutT(acc[mt][nt][r] * alpha + bv);
      }
    }
  }
}

// ---------------------------------------------------------------------------
// Tiled 64x64 transpose with optional fp32->bf16 convert.
// ---------------------------------------------------------------------------
template<typename T>
__global__ __launch_bounds__(256) void transpose_kernel(
    const T* __restrict__ in, u16* __restrict__ out, int R, int C,
    long long sIn, long long sOut)
{
  __shared__ u16 t[64][66];
  in  += (long long)blockIdx.z * sIn;
  out += (long long)blockIdx.z * sOut;
  const int r0 = blockIdx.y * 64, c0 = blockIdx.x * 64;
  const int tid = threadIdx.x;
  const int rr = tid >> 3, cc = (tid & 7) * 8;
  #pragma unroll
  for (int p = 0; p < 2; ++p) {
    union { uint4 u; unsigned w[4]; u16 h[8]; } v;
    const int row = rr + p * 32;
    load8(in + (long long)(r0 + row) * C + (c0 + cc), v.h);
    #pragma unroll
    for (int k = 0; k < 4; ++k)
      *(unsigned*)&t[row][cc + k * 2] = v.w[k];
  }
  __syncthreads();
  #pragma unroll
  for (int p = 0; p < 2; ++p) {
    const int oc = (tid >> 3) + p * 32;
    const int rc = (tid & 7) * 8;
    union { uint4 u; u16 h[8]; } g;
    #pragma unroll
    for (int j = 0; j < 8; ++j) g.h[j] = t[rc + j][oc];
    *(uint4*)(out + (long long)(c0 + oc) * R + (r0 + rc)) = g.u;
  }
}

// ---------------------------------------------------------------------------
// Elementwise fp32 -> bf16 convert (row-major), 8 elems/thread/iter.
// ---------------------------------------------------------------------------
__global__ __launch_bounds__(256) void cvt_kernel(
    const float* __restrict__ in, u16* __restrict__ out, int n8)
{
  const int stride = gridDim.x * 256;
  for (int i = blockIdx.x * 256 + threadIdx.x; i < n8; i += stride) {
    union { uint4 u; u16 h[8]; } v;
    load8(in + (long long)i * 8, v.h);
    *(uint4*)(out + (long long)i * 8) = v.u;
  }
}

// ---------------------------------------------------------------------------
// LayerNorm + ReLU over rows of 768 fp32 -> OutT. ReLU propagates NaN.
// ---------------------------------------------------------------------------
template<typename OutT>
__global__ __launch_bounds__(256) void ln_relu_kernel(
    const float* __restrict__ x, const float* __restrict__ g,
    const float* __restrict__ beta, OutT* __restrict__ out)
{
  __shared__ float sa[4], sb[4];
  const float* xr = x + (long long)blockIdx.x * 768;
  float v[3]; float s = 0.f, ss = 0.f;
  #pragma unroll
  for (int j = 0; j < 3; ++j) {
    v[j] = xr[threadIdx.x + j * 256];
    s += v[j]; ss += v[j] * v[j];
  }
  #pragma unroll
  for (int off = 32; off; off >>= 1) {
    s  += __shfl_down(s, off);
    ss += __shfl_down(ss, off);
  }
  const int w = threadIdx.x >> 6, lane = threadIdx.x & 63;
  if (!lane) { sa[w] = s; sb[w] = ss; }
  __syncthreads();
  s  = sa[0] + sa[1] + sa[2] + sa[3];
  ss = sb[0] + sb[1] + sb[2] + sb[3];
  const float mean = s * (1.f / 768.f);
  const float var  = ss * (1.f / 768.f) - mean * mean;
  const float rst  = rsqrtf(var + 1e-5f);
  OutT* orow = out + (long long)blockIdx.x * 768;
  #pragma unroll
  for (int j = 0; j < 3; ++j) {
    const int idx = threadIdx.x + j * 256;
    const float yv = (v[j] - mean) * rst * g[idx] + beta[idx];
    const float rv = (yv <= 0.f) ? 0.f : yv;  // NaN -> yv (propagates)
    orow[idx] = OutT(rv);
  }
}

// ---------------------------------------------------------------------------
// In-place row softmax over 2048 bf16 values (fp32 math)
// ---------------------------------------------------------------------------
__global__ __launch_bounds__(256) void softmax_kernel(u16* __restrict__ sim)
{
  __shared__ float sm[4], ssum[4];
  u16* row = sim + (long long)blockIdx.x * 2048;
  union { uint4 u; u16 h[8]; } v;
  v.u = *(const uint4*)(row + threadIdx.x * 8);
  float f[8]; float mx = -1e30f;
  #pragma unroll
  for (int j = 0; j < 8; ++j) { f[j] = b2f(v.h[j]); mx = fmaxf(mx, f[j]); }
  #pragma unroll
  for (int off = 32; off; off >>= 1) mx = fmaxf(mx, __shfl_down(mx, off));
  const int w = threadIdx.x >> 6, lane = threadIdx.x & 63;
  if (!lane) sm[w] = mx;
  __syncthreads();
  mx = fmaxf(fmaxf(sm[0], sm[1]), fmaxf(sm[2], sm[3]));
  float s = 0.f;
  #pragma unroll
  for (int j = 0; j < 8; ++j) { f[j] = __expf(f[j] - mx); s += f[j]; }
  #pragma unroll
  for (int off = 32; off; off >>= 1) s += __shfl_down(s, off);
  if (!lane) ssum[w] = s;
  __syncthreads();
  s = ssum[0] + ssum[1] + ssum[2] + ssum[3];
  const float inv = 1.f / s;
  #pragma unroll
  for (int j = 0; j < 8; ++j) v.h[j] = f2b(f[j] * inv);
  *(uint4*)(row + threadIdx.x * 8) = v.u;
}

// ---------------------------------------------------------------------------
// claw mean, two deterministic stages
// ---------------------------------------------------------------------------
__global__ __launch_bounds__(256) void claw_partial_kernel(
    const float* __restrict__ claw, float* __restrict__ partial, int n)
{
  __shared__ float sa[4];
  float s = 0.f;
  const int nv = n >> 2;
  for (int i = blockIdx.x * 256 + threadIdx.x; i < nv; i += 64 * 256) {
    float4 v = ((const float4*)claw)[i];
    s += v.x + v.y + v.z + v.w;
  }
  #pragma unroll
  for (int off = 32; off; off >>= 1) s += __shfl_down(s, off);
  const int w = threadIdx.x >> 6, lane = threadIdx.x & 63;
  if (!lane) sa[w] = s;
  __syncthreads();
  if (threadIdx.x == 0)
    partial[blockIdx.x] = sa[0] + sa[1] + sa[2] + sa[3];
}

__global__ void claw_final_kernel(
    const float* __restrict__ partial, float* __restrict__ scale, float inv)
{
  float s = partial[threadIdx.x];
  #pragma unroll
  for (int off = 32; off; off >>= 1) s += __shfl_down(s, off);
  if (threadIdx.x == 0) *scale = s * inv;
}

// ---------------------------------------------------------------------------
extern "C" void kernel_launch(void* const* d_in, const int* in_sizes, int n_in,
                              void* d_out, int out_size, void* d_ws, size_t ws_size,
                              hipStream_t stream)
{
  const float* vis   = (const float*)d_in[0];
  const float* lang  = (const float*)d_in[1];
  const float* vW    = (const float*)d_in[2];
  const float* vb    = (const float*)d_in[3];
  const float* vg    = (const float*)d_in[4];
  const float* vbeta = (const float*)d_in[5];
  const float* lW    = (const float*)d_in[6];
  const float* lb    = (const float*)d_in[7];
  const float* lg    = (const float*)d_in[8];
  const float* lbeta = (const float*)d_in[9];
  const float* claw  = (const float*)d_in[10];
  const float* oW    = (const float*)d_in[11];
  const float* ob    = (const float*)d_in[12];
  const float* og    = (const float*)d_in[13];
  const float* obeta = (const float*)d_in[14];
  float* out = (float*)d_out;

  constexpr int NB = 8, S = 2048, D = 768;
  constexpr int R = NB * S;                       // 16384
  constexpr long long SD = (long long)S * D;      // 1,572,864
  constexpr long long SS = (long long)S * S;      // 4,194,304
  const int nclaw = in_sizes[10];
  const float claw_inv = 1.0f / ((float)nclaw * 0.07f);
  const dim3 blk(256);
  const dim3 blk5(512);

  // Workspace layout (peak 167,772,432 B == proven floor from prior rounds).
  char* ws = (char*)d_ws;
  u16*   vp    = (u16*)  (ws);
  u16*   lp    = (u16*)  (ws + 25165824);
  u16*   visb  = (u16*)  (ws + 50331648);
  u16*   vpT   = (u16*)  (ws + 50331648);
  u16*   langb = (u16*)  (ws + 75497472);
  u16*   lpT   = (u16*)  (ws + 75497472);
  u16*   sim   = (u16*)  (ws + 100663296);
  float* y     = (float*)(ws + 100663296);
  u16*   vWT   = (u16*)  (ws + 150994944);
  u16*   lWT   = vWT + 589824;
  u16*   oWT   = (u16*)  (ws + 150994944);
  u16*   comb  = (u16*)  (ws);
  float* scale   = (float*)(ws + 167772160);
  float* partial = (float*)(ws + 167772176);

  claw_partial_kernel<<<64, blk, 0, stream>>>(claw, partial, nclaw);
  claw_final_kernel<<<1, 64, 0, stream>>>(partial, scale, claw_inv);

  // Weight transposes: W[k][n] fp32 -> WT[n][k] bf16 (direct B operands)
  transpose_kernel<float><<<dim3(12, 12, 1), blk, 0, stream>>>(
      vW, vWT, D, D, 0, 0);
  transpose_kernel<float><<<dim3(12, 12, 1), blk, 0, stream>>>(
      lW, lWT, D, D, 0, 0);

  // vision: visb = bf16(vis); y = visb @ vWT^T + vb; vp = relu(LN(y)); vpT
  cvt_kernel<<<2048, blk, 0, stream>>>(vis, visb, (int)(R * D / 8));
  gemm256<float><<<dim3(D / 256, R / 256, 1), blk5, 0, stream>>>(
      visb, vWT, vb, nullptr, y, D, D, D, D, 0, 0, 0);
  ln_relu_kernel<__hip_bfloat16><<<R, blk, 0, stream>>>(
      y, vg, vbeta, (__hip_bfloat16*)vp);
  transpose_kernel<u16><<<dim3(D / 64, S / 64, NB), blk, 0, stream>>>(
      vp, vpT, S, D, SD, SD);

  // language
  cvt_kernel<<<2048, blk, 0, stream>>>(lang, langb, (int)(R * D / 8));
  gemm256<float><<<dim3(D / 256, R / 256, 1), blk5, 0, stream>>>(
      langb, lWT, lb, nullptr, y, D, D, D, D, 0, 0, 0);
  ln_relu_kernel<__hip_bfloat16><<<R, blk, 0, stream>>>(
      y, lg, lbeta, (__hip_bfloat16*)lp);
  transpose_kernel<u16><<<dim3(D / 64, S / 64, NB), blk, 0, stream>>>(
      lp, lpT, S, D, SD, SD);

  // sim[z] = (vp[z] @ lp[z]^T) * scale
  gemm256<__hip_bfloat16><<<dim3(S / 256, S / 256, NB), blk5, 0, stream>>>(
      vp, lp, nullptr, scale, (__hip_bfloat16*)sim, D, D, D, S, SD, SD, SS);
  softmax_kernel<<<R, blk, 0, stream>>>(sim);

  // aligned_vision[z] = A[z] @ vp[z] -> comb[:, 0:768]  (direct via vpT)
  gemm256<__hip_bfloat16><<<dim3(D / 256, S / 256, NB), blk5, 0, stream>>>(
      sim, vpT, nullptr, nullptr, (__hip_bfloat16*)comb,
      S, S, S, 2 * D, SS, SD, 2 * SD);
  // aligned_language[z] = A[z]^T @ lp[z] -> comb[:, 768:1536]
  // (A scatter over sim; B direct via lpT) - stays on the 128^2 kernel.
  gemm128<1, 0, __hip_bfloat16><<<dim3(D / 128, S / 128, NB), blk, 0, stream>>>(
      sim, lpT, nullptr, nullptr, (__hip_bfloat16*)comb + D,
      S, S, S, 2 * D, SS, SD, 2 * SD);

  // oWT (sim region dead past here except y overlay)
  transpose_kernel<float><<<dim3(12, 24, 1), blk, 0, stream>>>(
      oW, oWT, 2 * D, D, 0, 0);

  // out = relu(LN(comb @ oWT^T + ob))
  gemm256<float><<<dim3(D / 256, R / 256, 1), blk5, 0, stream>>>(
      comb, oWT, ob, nullptr, y, 2 * D, 2 * D, 2 * D, D, 0, 0, 0);
  ln_relu_kernel<float><<<R, blk, 0, stream>>>(y, og, obeta, out);
}

// Round 6
// 585.268 us; speedup vs baseline: 1.1547x; 1.0147x over previous
//
#include <hip/hip_runtime.h>
#include <hip/hip_bf16.h>

typedef short short8 __attribute__((ext_vector_type(8)));
typedef float f32x4 __attribute__((ext_vector_type(4)));
typedef unsigned short u16;

#define BK 32
// Swizzled LDS layout for scatter-staged operands (gemm128 MA==1 path only).
static __device__ __forceinline__ int sw(int row, int g) {
  return row * 32 + ((g ^ ((row >> 3) & 3)) << 3);
}

// fp32 -> bf16 round-to-nearest-even (payload as u16)
static __device__ __forceinline__ u16 f2b(float f) {
  union { float f; unsigned u; } x; x.f = f;
  unsigned r = x.u + 0x7FFF + ((x.u >> 16) & 1);
  return (u16)(r >> 16);
}
static __device__ __forceinline__ float b2f(u16 u) {
  unsigned int x = ((unsigned int)u) << 16;
  float f; __builtin_memcpy(&f, &x, 4);
  return f;
}

static __device__ __forceinline__ void load8(const u16* p, u16* dst) {
  union { uint4 u; u16 h[8]; } t;
  t.u = *(const uint4*)p;
  #pragma unroll
  for (int j = 0; j < 8; ++j) dst[j] = t.h[j];
}
static __device__ __forceinline__ void load8(const float* p, u16* dst) {
  float4 a = ((const float4*)p)[0];
  float4 b = ((const float4*)p)[1];
  dst[0] = f2b(a.x); dst[1] = f2b(a.y); dst[2] = f2b(a.z); dst[3] = f2b(a.w);
  dst[4] = f2b(b.x); dst[5] = f2b(b.y); dst[6] = f2b(b.z); dst[7] = f2b(b.w);
}

// Async global->LDS, 16B per lane (gfx950 global_load_lds_dwordx4).
// LDS dest must be wave-uniform base + lane*16 (m104/m108 caveat).
static __device__ __forceinline__ void gl_lds16(const u16* g, u16* l) {
  __builtin_amdgcn_global_load_lds(
      (const __attribute__((address_space(1))) unsigned int*)g,
      (__attribute__((address_space(3))) unsigned int*)l, 16, 0, 0);
}

// Inline-asm ds_read_b128: opaque to SIInsertWaitcnts, so the LDS-DMA
// (global_load_lds) alias tracking cannot force a vmcnt(0) drain before it.
// "=&v" early-clobber: address VGPR never aliases the destination quad.
// Caller does s_waitcnt lgkmcnt(0) + sched_barrier(0) before use (rule 18).
template<int OFF>
static __device__ __forceinline__ short8 dsr128(unsigned addr) {
  short8 d;
  asm volatile("ds_read_b128 %0, %1 offset:%2"
               : "=&v"(d) : "v"(addr), "n"(OFF));
  return d;
}
// 32-bit LDS byte offset of a __shared__ pointer (addrspacecast to AS3).
static __device__ __forceinline__ unsigned lds_off(const u16* p) {
  return (unsigned)(unsigned long long)
      (const __attribute__((address_space(3))) u16*)p;
}

// ---------------------------------------------------------------------------
// 256x256x64 pipelined MFMA GEMM, free-running waves, 1 barrier / K-tile:
//   C[z] = (A[z] @ B[z]^T) * alpha + bias, A:[M][K], B:[N][K], bf16 payloads.
// 512 threads = 8 waves (2M x 4N); per-wave output 128x64 = 8x4 16x16 frags.
// LDS: A,B each 2 x 256x64 bf16 (dbuf) = 128 KiB (1 block/CU, 2 waves/SIMD).
//
// Swizzle: row stride = 128B = exact bank wrap; element (r,g16) stored at
// granule g^(r&7) -> uniform 8 lanes/bank-group on every ds_read_b128.
// gl_lds dest stays LINEAR; inverse permutation applied to the GLOBAL source
// column (srcg), reads swizzled (rule 21).
//
// Sync design (v4): with strict double-buffering, waves only READ the
// current buffer within a group - no intra-group cross-wave hazard exists.
// All 8 barriers/K-tile of the lockstep schedule are replaced by ONE
// boundary barrier per K-tile (buffer swap point). Load ledger:
//   group t P1 issues ALL 8 loads of tile t+1 into buf[(t+1)&1]
//   (order: A c0,c1, B h0 x2, B h1 x2, A c2,c3) - that buffer was finished
//   by ALL waves at the end of group t-1 (boundary barrier), so no WAR.
//   Loop-top boundary: vmcnt(2) [first-6 of tile t landed; its c2,c3 may
//   still fly] + s_barrier [cross-wave visibility of all waves' DMAs].
//   Before P2's ds_reads (rows 64-127/192-255 = c2,c3 data): vmcnt(8)
//   steady-state (8 fresh issues outstanding) / vmcnt(0) at tail.
// Per-wave lgkmcnt(0)+sched_barrier(0) orders each phase's ds_reads before
// its MFMA cluster (rule 18). Waves free-run across phases; setprio(1)
// around MFMA arbitrates the genuinely role-diverse waves (T5).
// MFMA order per acc unchanged (ks0 then ks1) -> bit-identical results.
// Requires M,N % 256 == 0, K % 64 == 0 (NT >= 2).
// ---------------------------------------------------------------------------
template<typename OutT>
__global__ __launch_bounds__(512, 2) void gemm256(
    const u16* __restrict__ A, const u16* __restrict__ B,
    const float* __restrict__ bias, const float* __restrict__ alpha_ptr,
    OutT* __restrict__ C, int K, int lda, int ldb, int ldc,
    long long sA, long long sB, long long sC)
{
  __shared__ u16 As[2][256 * 64];  // 64 KB
  __shared__ u16 Bs[2][256 * 64];  // 64 KB

  A += (long long)blockIdx.z * sA;
  B += (long long)blockIdx.z * sB;
  C += (long long)blockIdx.z * sC;

  const int tid  = threadIdx.x;
  const int m0   = blockIdx.y * 256;
  const int n0   = blockIdx.x * 256;
  const int w    = tid >> 6, lane = tid & 63;
  const int wm   = (w >> 2) * 128;   // 0 / 128
  const int wn   = (w & 3) * 64;     // 0..192
  const int lrow = lane & 15;
  const int lg   = lane >> 4;                     // k-granule 0..3
  const int xa   = lrow & 7;                      // read-side swizzle phase
  const int sr   = tid >> 3;                      // staging row-lane 0..63
  const int srcg = (tid & 7) ^ ((tid >> 3) & 7);  // inverse-swizzled src col
  const int NT   = K >> 6;

  f32x4 acc[8][4] = {};

  // staging: dest is linear (wave-uniform base + lane*16B); source column
  // carries the inverse swizzle so that logical (r,g) lands at g^(r&7).
  auto stA = [&](int t, int c) {
    u16* lb = As[t & 1];
    const int r = (sr < 32) ? (32 * c + sr) : (96 + 32 * c + sr);
    gl_lds16(A + (long long)(m0 + r) * lda + (t * 64 + srcg * 8),
             lb + r * 64 + (tid & 7) * 8);
  };
  auto stB = [&](int t, int h) {
    u16* lb = Bs[t & 1];
    #pragma unroll
    for (int l = 0; l < 2; ++l) {
      const int r = 128 * h + 64 * l + sr;
      gl_lds16(B + (long long)(n0 + r) * ldb + (t * 64 + srcg * 8),
               lb + r * 64 + (tid & 7) * 8);
    }
  };
  // issue all 8 loads of tile t (order fixes the vmcnt ledger:
  // oldest-6 = c0,c1,B; newest-2 = c2,c3)
  auto issueTile = [&](int t) {
    stA(t, 0); stA(t, 1); stB(t, 0); stB(t, 1); stA(t, 2); stA(t, 3);
  };

  // Precomputed 32-bit LDS read addresses (buf0; buf1 = +32768 B).
  const unsigned aRow = lds_off(&As[0][0]) + (wm + lrow) * 128;
  const unsigned bRow = lds_off(&Bs[0][0]) + (wn + lrow) * 128;
  const unsigned gk0  = (unsigned)((lg ^ xa) << 4);
  const unsigned gk1  = (unsigned)(((4 + lg) ^ xa) << 4);

  // --- prologue: tile0's 8 loads in flight ---
  issueTile(0);

  short8 af[4], bfr[4];
  for (int t = 0; t < NT; ++t) {
    const unsigned ab = aRow + ((t & 1) << 15);
    const unsigned bb = bRow + ((t & 1) << 15);
    const unsigned a0 = ab + gk0, a1 = ab + gk1;
    const unsigned b0 = bb + gk0, b1 = bb + gk1;

    // ---- boundary: first-6 of tile t landed (all waves), buffers swap ----
    asm volatile("s_waitcnt vmcnt(2)" ::: "memory");
    __builtin_amdgcn_s_barrier();
    __builtin_amdgcn_sched_barrier(0);

    // ---- P1: A mt0-3 ks0 + B ks0; issue ALL of tile t+1 ----
    af[0] = dsr128<0>(a0);    af[1] = dsr128<2048>(a0);
    af[2] = dsr128<4096>(a0); af[3] = dsr128<6144>(a0);
    bfr[0] = dsr128<0>(b0);    bfr[1] = dsr128<2048>(b0);
    bfr[2] = dsr128<4096>(b0); bfr[3] = dsr128<6144>(b0);
    if (t + 1 < NT) issueTile(t + 1);
    asm volatile("s_waitcnt lgkmcnt(0)");
    __builtin_amdgcn_sched_barrier(0);
    __builtin_amdgcn_s_setprio(1);
    #pragma unroll
    for (int mt = 0; mt < 4; ++mt)
      #pragma unroll
      for (int nt = 0; nt < 4; ++nt)
        acc[mt][nt] = __builtin_amdgcn_mfma_f32_16x16x32_bf16(
            af[mt], bfr[nt], acc[mt][nt], 0, 0, 0);
    __builtin_amdgcn_s_setprio(0);

    // ---- P2: A mt4-7 ks0 (c2,c3 rows: guard with counted vmcnt) ----
    if (t + 1 < NT)
      asm volatile("s_waitcnt vmcnt(8)" ::: "memory");
    else
      asm volatile("s_waitcnt vmcnt(0)" ::: "memory");
    af[0] = dsr128<8192>(a0);  af[1] = dsr128<10240>(a0);
    af[2] = dsr128<12288>(a0); af[3] = dsr128<14336>(a0);
    asm volatile("s_waitcnt lgkmcnt(0)");
    __builtin_amdgcn_sched_barrier(0);
    __builtin_amdgcn_s_setprio(1);
    #pragma unroll
    for (int mt = 0; mt < 4; ++mt)
      #pragma unroll
      for (int nt = 0; nt < 4; ++nt)
        acc[4 + mt][nt] = __builtin_amdgcn_mfma_f32_16x16x32_bf16(
            af[mt], bfr[nt], acc[4 + mt][nt], 0, 0, 0);
    __builtin_amdgcn_s_setprio(0);

    // ---- P3: A mt0-3 ks1 + B ks1 ----
    af[0] = dsr128<0>(a1);    af[1] = dsr128<2048>(a1);
    af[2] = dsr128<4096>(a1); af[3] = dsr128<6144>(a1);
    bfr[0] = dsr128<0>(b1);    bfr[1] = dsr128<2048>(b1);
    bfr[2] = dsr128<4096>(b1); bfr[3] = dsr128<6144>(b1);
    asm volatile("s_waitcnt lgkmcnt(0)");
    __builtin_amdgcn_sched_barrier(0);
    __builtin_amdgcn_s_setprio(1);
    #pragma unroll
    for (int mt = 0; mt < 4; ++mt)
      #pragma unroll
      for (int nt = 0; nt < 4; ++nt)
        acc[mt][nt] = __builtin_amdgcn_mfma_f32_16x16x32_bf16(
            af[mt], bfr[nt], acc[mt][nt], 0, 0, 0);
    __builtin_amdgcn_s_setprio(0);

    // ---- P4: A mt4-7 ks1 ----
    af[0] = dsr128<8192>(a1);  af[1] = dsr128<10240>(a1);
    af[2] = dsr128<12288>(a1); af[3] = dsr128<14336>(a1);
    asm volatile("s_waitcnt lgkmcnt(0)");
    __builtin_amdgcn_sched_barrier(0);
    __builtin_amdgcn_s_setprio(1);
    #pragma unroll
    for (int mt = 0; mt < 4; ++mt)
      #pragma unroll
      for (int nt = 0; nt < 4; ++nt)
        acc[4 + mt][nt] = __builtin_amdgcn_mfma_f32_16x16x32_bf16(
            af[mt], bfr[nt], acc[4 + mt][nt], 0, 0, 0);
    __builtin_amdgcn_s_setprio(0);
  }

  const float alpha = alpha_ptr ? *alpha_ptr : 1.0f;
  #pragma unroll
  for (int nt = 0; nt < 4; ++nt) {
    const int n = n0 + wn + nt * 16 + lrow;
    const float bv = bias ? bias[n] : 0.0f;
    #pragma unroll
    for (int mt = 0; mt < 8; ++mt)
      #pragma unroll
      for (int r = 0; r < 4; ++r) {
        const int m = m0 + wm + mt * 16 + lg * 4 + r;
        C[(long long)m * ldc + n] = OutT(acc[mt][nt][r] * alpha + bv);
      }
  }
}

// ---------------------------------------------------------------------------
// 128x128x32 MFMA GEMM (m97 structure), kept for the A^T scatter case only.
//   MA==1: A is k-strided [K][M] (sim columns); swizzled scalar LDS scatter.
//   MB==0: B direct bf16 [N][K] via global_load_lds.
// ---------------------------------------------------------------------------
template<int MA, int MB, typename OutT>
__global__ __launch_bounds__(256) void gemm128(
    const u16* __restrict__ A, const u16* __restrict__ B,
    const float* __restrict__ bias, const float* __restrict__ alpha_ptr,
    OutT* __restrict__ C, int K, int lda, int ldb, int ldc,
    long long sA, long long sB, long long sC)
{
  __shared__ u16 As[128 * 32];
  __shared__ u16 Bs[128 * 32];

  A += (long long)blockIdx.z * sA;
  B += (long long)blockIdx.z * sB;
  C += (long long)blockIdx.z * sC;

  const int tid  = threadIdx.x;
  const int m0   = blockIdx.y * 128;
  const int n0   = blockIdx.x * 128;
  const int w    = tid >> 6, lane = tid & 63;
  const int wm   = (w >> 1) * 64;
  const int wn   = (w & 1) * 64;
  const int lrow = lane & 15;
  const int lg   = lane >> 4;

  int aoff[4], boff[4];
  #pragma unroll
  for (int t = 0; t < 4; ++t) {
    const int ar = wm + t * 16 + lrow;
    const int br = wn + t * 16 + lrow;
    aoff[t] = (MA == 1) ? sw(ar, lg) : ar * 32 + lg * 8;
    boff[t] = (MB == 1) ? sw(br, lg) : br * 32 + lg * 8;
  }

  f32x4 acc[4][4] = {};

  for (int k0 = 0; k0 < K; k0 += BK) {
    if constexpr (MA == 0) {
      gl_lds16(A + (long long)(m0 + (tid >> 2)) * lda + (k0 + (tid & 3) * 8),
               As + tid * 8);
      gl_lds16(A + (long long)(m0 + 64 + (tid >> 2)) * lda + (k0 + (tid & 3) * 8),
               As + 2048 + tid * 8);
    } else {
      const int kk = tid >> 3;
      #pragma unroll
      for (int p = 0; p < 2; ++p) {
        const int rr = (tid & 7) * 8 + p * 64;
        u16 h[8];
        load8(A + (long long)(k0 + kk) * lda + (m0 + rr), h);
        #pragma unroll
        for (int j = 0; j < 8; ++j) As[sw(rr + j, kk >> 3) + (kk & 7)] = h[j];
      }
    }
    if constexpr (MB == 0) {
      gl_lds16(B + (long long)(n0 + (tid >> 2)) * ldb + (k0 + (tid & 3) * 8),
               Bs + tid * 8);
      gl_lds16(B + (long long)(n0 + 64 + (tid >> 2)) * ldb + (k0 + (tid & 3) * 8),
               Bs + 2048 + tid * 8);
    } else {
      const int kk = tid >> 3;
      #pragma unroll
      for (int p = 0; p < 2; ++p) {
        const int rr = (tid & 7) * 8 + p * 64;
        u16 h[8];
        load8(B + (long long)(k0 + kk) * ldb + (n0 + rr), h);
        #pragma unroll
        for (int j = 0; j < 8; ++j) Bs[sw(rr + j, kk >> 3) + (kk & 7)] = h[j];
      }
    }
    __syncthreads();

    short8 af[4], bf[4];
    #pragma unroll
    for (int t = 0; t < 4; ++t) af[t] = *(const short8*)(As + aoff[t]);
    #pragma unroll
    for (int t = 0; t < 4; ++t) bf[t] = *(const short8*)(Bs + boff[t]);
    #pragma unroll
    for (int mt = 0; mt < 4; ++mt)
      #pragma unroll
      for (int nt = 0; nt < 4; ++nt)
        acc[mt][nt] = __builtin_amdgcn_mfma_f32_16x16x32_bf16(
            af[mt], bf[nt], acc[mt][nt], 0, 0, 0);
    __syncthreads();
  }

  const float alpha = alpha_ptr ? *alpha_ptr : 1.0f;
  #pragma unroll
  for (int nt = 0; nt < 4; ++nt) {
    const int n = n0 + wn + nt * 16 + lrow;
    const float bv = bias ? bias[n] : 0.0f;
    #pragma unroll
    for (int mt = 0; mt < 4; ++mt) {
      #pragma unroll
      for (int r = 0; r < 4; ++r) {
        const int m = m0 + wm + mt * 16 + lg * 4 + r;
        C[(long long)m * ldc + n] = OutT(acc[mt][nt][r] * alpha + bv);
      }
    }
  }
}

// ---------------------------------------------------------------------------
// Tiled 64x64 transpose with optional fp32->bf16 convert.
// ---------------------------------------------------------------------------
template<typename T>
__global__ __launch_bounds__(256) void transpose_kernel(
    const T* __restrict__ in, u16* __restrict__ out, int R, int C,
    long long sIn, long long sOut)
{
  __shared__ u16 t[64][66];
  in  += (long long)blockIdx.z * sIn;
  out += (long long)blockIdx.z * sOut;
  const int r0 = blockIdx.y * 64, c0 = blockIdx.x * 64;
  const int tid = threadIdx.x;
  const int rr = tid >> 3, cc = (tid & 7) * 8;
  #pragma unroll
  for (int p = 0; p < 2; ++p) {
    union { uint4 u; unsigned w[4]; u16 h[8]; } v;
    const int row = rr + p * 32;
    load8(in + (long long)(r0 + row) * C + (c0 + cc), v.h);
    #pragma unroll
    for (int k = 0; k < 4; ++k)
      *(unsigned*)&t[row][cc + k * 2] = v.w[k];
  }
  __syncthreads();
  #pragma unroll
  for (int p = 0; p < 2; ++p) {
    const int oc = (tid >> 3) + p * 32;
    const int rc = (tid & 7) * 8;
    union { uint4 u; u16 h[8]; } g;
    #pragma unroll
    for (int j = 0; j < 8; ++j) g.h[j] = t[rc + j][oc];
    *(uint4*)(out + (long long)(c0 + oc) * R + (r0 + rc)) = g.u;
  }
}

// ---------------------------------------------------------------------------
// Elementwise fp32 -> bf16 convert (row-major), 8 elems/thread/iter.
// ---------------------------------------------------------------------------
__global__ __launch_bounds__(256) void cvt_kernel(
    const float* __restrict__ in, u16* __restrict__ out, int n8)
{
  const int stride = gridDim.x * 256;
  for (int i = blockIdx.x * 256 + threadIdx.x; i < n8; i += stride) {
    union { uint4 u; u16 h[8]; } v;
    load8(in + (long long)i * 8, v.h);
    *(uint4*)(out + (long long)i * 8) = v.u;
  }
}

// ---------------------------------------------------------------------------
// LayerNorm + ReLU over rows of 768 fp32 -> OutT. ReLU propagates NaN.
// ---------------------------------------------------------------------------
template<typename OutT>
__global__ __launch_bounds__(256) void ln_relu_kernel(
    const float* __restrict__ x, const float* __restrict__ g,
    const float* __restrict__ beta, OutT* __restrict__ out)
{
  __shared__ float sa[4], sb[4];
  const float* xr = x + (long long)blockIdx.x * 768;
  float v[3]; float s = 0.f, ss = 0.f;
  #pragma unroll
  for (int j = 0; j < 3; ++j) {
    v[j] = xr[threadIdx.x + j * 256];
    s += v[j]; ss += v[j] * v[j];
  }
  #pragma unroll
  for (int off = 32; off; off >>= 1) {
    s  += __shfl_down(s, off);
    ss += __shfl_down(ss, off);
  }
  const int w = threadIdx.x >> 6, lane = threadIdx.x & 63;
  if (!lane) { sa[w] = s; sb[w] = ss; }
  __syncthreads();
  s  = sa[0] + sa[1] + sa[2] + sa[3];
  ss = sb[0] + sb[1] + sb[2] + sb[3];
  const float mean = s * (1.f / 768.f);
  const float var  = ss * (1.f / 768.f) - mean * mean;
  const float rst  = rsqrtf(var + 1e-5f);
  OutT* orow = out + (long long)blockIdx.x * 768;
  #pragma unroll
  for (int j = 0; j < 3; ++j) {
    const int idx = threadIdx.x + j * 256;
    const float yv = (v[j] - mean) * rst * g[idx] + beta[idx];
    const float rv = (yv <= 0.f) ? 0.f : yv;  // NaN -> yv (propagates)
    orow[idx] = OutT(rv);
  }
}

// ---------------------------------------------------------------------------
// In-place row softmax over 2048 bf16 values (fp32 math)
// ---------------------------------------------------------------------------
__global__ __launch_bounds__(256) void softmax_kernel(u16* __restrict__ sim)
{
  __shared__ float sm[4], ssum[4];
  u16* row = sim + (long long)blockIdx.x * 2048;
  union { uint4 u; u16 h[8]; } v;
  v.u = *(const uint4*)(row + threadIdx.x * 8);
  float f[8]; float mx = -1e30f;
  #pragma unroll
  for (int j = 0; j < 8; ++j) { f[j] = b2f(v.h[j]); mx = fmaxf(mx, f[j]); }
  #pragma unroll
  for (int off = 32; off; off >>= 1) mx = fmaxf(mx, __shfl_down(mx, off));
  const int w = threadIdx.x >> 6, lane = threadIdx.x & 63;
  if (!lane) sm[w] = mx;
  __syncthreads();
  mx = fmaxf(fmaxf(sm[0], sm[1]), fmaxf(sm[2], sm[3]));
  float s = 0.f;
  #pragma unroll
  for (int j = 0; j < 8; ++j) { f[j] = __expf(f[j] - mx); s += f[j]; }
  #pragma unroll
  for (int off = 32; off; off >>= 1) s += __shfl_down(s, off);
  if (!lane) ssum[w] = s;
  __syncthreads();
  s = ssum[0] + ssum[1] + ssum[2] + ssum[3];
  const float inv = 1.f / s;
  #pragma unroll
  for (int j = 0; j < 8; ++j) v.h[j] = f2b(f[j] * inv);
  *(uint4*)(row + threadIdx.x * 8) = v.u;
}

// ---------------------------------------------------------------------------
// claw mean, two deterministic stages
// ---------------------------------------------------------------------------
__global__ __launch_bounds__(256) void claw_partial_kernel(
    const float* __restrict__ claw, float* __restrict__ partial, int n)
{
  __shared__ float sa[4];
  float s = 0.f;
  const int nv = n >> 2;
  for (int i = blockIdx.x * 256 + threadIdx.x; i < nv; i += 64 * 256) {
    float4 v = ((const float4*)claw)[i];
    s += v.x + v.y + v.z + v.w;
  }
  #pragma unroll
  for (int off = 32; off; off >>= 1) s += __shfl_down(s, off);
  const int w = threadIdx.x >> 6, lane = threadIdx.x & 63;
  if (!lane) sa[w] = s;
  __syncthreads();
  if (threadIdx.x == 0)
    partial[blockIdx.x] = sa[0] + sa[1] + sa[2] + sa[3];
}

__global__ void claw_final_kernel(
    const float* __restrict__ partial, float* __restrict__ scale, float inv)
{
  float s = partial[threadIdx.x];
  #pragma unroll
  for (int off = 32; off; off >>= 1) s += __shfl_down(s, off);
  if (threadIdx.x == 0) *scale = s * inv;
}

// ---------------------------------------------------------------------------
extern "C" void kernel_launch(void* const* d_in, const int* in_sizes, int n_in,
                              void* d_out, int out_size, void* d_ws, size_t ws_size,
                              hipStream_t stream)
{
  const float* vis   = (const float*)d_in[0];
  const float* lang  = (const float*)d_in[1];
  const float* vW    = (const float*)d_in[2];
  const float* vb    = (const float*)d_in[3];
  const float* vg    = (const float*)d_in[4];
  const float* vbeta = (const float*)d_in[5];
  const float* lW    = (const float*)d_in[6];
  const float* lb    = (const float*)d_in[7];
  const float* lg    = (const float*)d_in[8];
  const float* lbeta = (const float*)d_in[9];
  const float* claw  = (const float*)d_in[10];
  const float* oW    = (const float*)d_in[11];
  const float* ob    = (const float*)d_in[12];
  const float* og    = (const float*)d_in[13];
  const float* obeta = (const float*)d_in[14];
  float* out = (float*)d_out;

  constexpr int NB = 8, S = 2048, D = 768;
  constexpr int R = NB * S;                       // 16384
  constexpr long long SD = (long long)S * D;      // 1,572,864
  constexpr long long SS = (long long)S * S;      // 4,194,304
  const int nclaw = in_sizes[10];
  const float claw_inv = 1.0f / ((float)nclaw * 0.07f);
  const dim3 blk(256);
  const dim3 blk5(512);

  // Workspace layout (peak 167,772,432 B == proven floor from prior rounds).
  char* ws = (char*)d_ws;
  u16*   vp    = (u16*)  (ws);
  u16*   lp    = (u16*)  (ws + 25165824);
  u16*   visb  = (u16*)  (ws + 50331648);
  u16*   vpT   = (u16*)  (ws + 50331648);
  u16*   langb = (u16*)  (ws + 75497472);
  u16*   lpT   = (u16*)  (ws + 75497472);
  u16*   sim   = (u16*)  (ws + 100663296);
  float* y     = (float*)(ws + 100663296);
  u16*   vWT   = (u16*)  (ws + 150994944);
  u16*   lWT   = vWT + 589824;
  u16*   oWT   = (u16*)  (ws + 150994944);
  u16*   comb  = (u16*)  (ws);
  float* scale   = (float*)(ws + 167772160);
  float* partial = (float*)(ws + 167772176);

  claw_partial_kernel<<<64, blk, 0, stream>>>(claw, partial, nclaw);
  claw_final_kernel<<<1, 64, 0, stream>>>(partial, scale, claw_inv);

  // Weight transposes: W[k][n] fp32 -> WT[n][k] bf16 (direct B operands)
  transpose_kernel<float><<<dim3(12, 12, 1), blk, 0, stream>>>(
      vW, vWT, D, D, 0, 0);
  transpose_kernel<float><<<dim3(12, 12, 1), blk, 0, stream>>>(
      lW, lWT, D, D, 0, 0);

  // vision: visb = bf16(vis); y = visb @ vWT^T + vb; vp = relu(LN(y)); vpT
  cvt_kernel<<<2048, blk, 0, stream>>>(vis, visb, (int)(R * D / 8));
  gemm256<float><<<dim3(D / 256, R / 256, 1), blk5, 0, stream>>>(
      visb, vWT, vb, nullptr, y, D, D, D, D, 0, 0, 0);
  ln_relu_kernel<__hip_bfloat16><<<R, blk, 0, stream>>>(
      y, vg, vbeta, (__hip_bfloat16*)vp);
  transpose_kernel<u16><<<dim3(D / 64, S / 64, NB), blk, 0, stream>>>(
      vp, vpT, S, D, SD, SD);

  // language
  cvt_kernel<<<2048, blk, 0, stream>>>(lang, langb, (int)(R * D / 8));
  gemm256<float><<<dim3(D / 256, R / 256, 1), blk5, 0, stream>>>(
      langb, lWT, lb, nullptr, y, D, D, D, D, 0, 0, 0);
  ln_relu_kernel<__hip_bfloat16><<<R, blk, 0, stream>>>(
      y, lg, lbeta, (__hip_bfloat16*)lp);
  transpose_kernel<u16><<<dim3(D / 64, S / 64, NB), blk, 0, stream>>>(
      lp, lpT, S, D, SD, SD);

  // sim[z] = (vp[z] @ lp[z]^T) * scale
  gemm256<__hip_bfloat16><<<dim3(S / 256, S / 256, NB), blk5, 0, stream>>>(
      vp, lp, nullptr, scale, (__hip_bfloat16*)sim, D, D, D, S, SD, SD, SS);
  softmax_kernel<<<R, blk, 0, stream>>>(sim);

  // aligned_vision[z] = A[z] @ vp[z] -> comb[:, 0:768]  (direct via vpT)
  gemm256<__hip_bfloat16><<<dim3(D / 256, S / 256, NB), blk5, 0, stream>>>(
      sim, vpT, nullptr, nullptr, (__hip_bfloat16*)comb,
      S, S, S, 2 * D, SS, SD, 2 * SD);
  // aligned_language[z] = A[z]^T @ lp[z] -> comb[:, 768:1536]
  // (A scatter over sim; B direct via lpT) - stays on the 128^2 kernel.
  gemm128<1, 0, __hip_bfloat16><<<dim3(D / 128, S / 128, NB), blk, 0, stream>>>(
      sim, lpT, nullptr, nullptr, (__hip_bfloat16*)comb + D,
      S, S, S, 2 * D, SS, SD, 2 * SD);

  // oWT (sim region dead past here except y overlay)
  transpose_kernel<float><<<dim3(12, 24, 1), blk, 0, stream>>>(
      oW, oWT, 2 * D, D, 0, 0);

  // out = relu(LN(comb @ oWT^T + ob))
  gemm256<float><<<dim3(D / 256, R / 256, 1), blk5, 0, stream>>>(
      comb, oWT, ob, nullptr, y, 2 * D, 2 * D, 2 * D, D, 0, 0, 0);
  ln_relu_kernel<float><<<R, blk, 0, stream>>>(y, og, obeta, out);
}

// Round 7
// 580.698 us; speedup vs baseline: 1.1638x; 1.0079x over previous
//
#include <hip/hip_runtime.h>
#include <hip/hip_bf16.h>

typedef short short8 __attribute__((ext_vector_type(8)));
typedef float f32x4 __attribute__((ext_vector_type(4)));
typedef unsigned short u16;

#define BK 32
// Swizzled LDS layout for scatter-staged operands (gemm128 MA==1 path only).
static __device__ __forceinline__ int sw(int row, int g) {
  return row * 32 + ((g ^ ((row >> 3) & 3)) << 3);
}

// fp32 -> bf16 round-to-nearest-even (payload as u16)
static __device__ __forceinline__ u16 f2b(float f) {
  union { float f; unsigned u; } x; x.f = f;
  unsigned r = x.u + 0x7FFF + ((x.u >> 16) & 1);
  return (u16)(r >> 16);
}
static __device__ __forceinline__ float b2f(u16 u) {
  unsigned int x = ((unsigned int)u) << 16;
  float f; __builtin_memcpy(&f, &x, 4);
  return f;
}

static __device__ __forceinline__ void load8(const u16* p, u16* dst) {
  union { uint4 u; u16 h[8]; } t;
  t.u = *(const uint4*)p;
  #pragma unroll
  for (int j = 0; j < 8; ++j) dst[j] = t.h[j];
}
static __device__ __forceinline__ void load8(const float* p, u16* dst) {
  float4 a = ((const float4*)p)[0];
  float4 b = ((const float4*)p)[1];
  dst[0] = f2b(a.x); dst[1] = f2b(a.y); dst[2] = f2b(a.z); dst[3] = f2b(a.w);
  dst[4] = f2b(b.x); dst[5] = f2b(b.y); dst[6] = f2b(b.z); dst[7] = f2b(b.w);
}

// Async global->LDS, 16B per lane (gfx950 global_load_lds_dwordx4).
// LDS dest must be wave-uniform base + lane*16 (m104/m108 caveat).
static __device__ __forceinline__ void gl_lds16(const u16* g, u16* l) {
  __builtin_amdgcn_global_load_lds(
      (const __attribute__((address_space(1))) unsigned int*)g,
      (__attribute__((address_space(3))) unsigned int*)l, 16, 0, 0);
}

// Inline-asm ds_read_b128: opaque to SIInsertWaitcnts, so the LDS-DMA
// (global_load_lds) alias tracking cannot force a vmcnt(0) drain before it.
// "=&v" early-clobber: address VGPR never aliases the destination quad.
// Caller gates consumers with counted s_waitcnt lgkmcnt + sched_barrier(0)
// (rule 18: MFMA hoists past asm waitcnt without the sched_barrier fence).
template<int OFF>
static __device__ __forceinline__ short8 dsr128(unsigned addr) {
  short8 d;
  asm volatile("ds_read_b128 %0, %1 offset:%2"
               : "=&v"(d) : "v"(addr), "n"(OFF));
  return d;
}
// 32-bit LDS byte offset of a __shared__ pointer (addrspacecast to AS3).
static __device__ __forceinline__ unsigned lds_off(const u16* p) {
  return (unsigned)(unsigned long long)
      (const __attribute__((address_space(3))) u16*)p;
}

#define LGKM(N) do { \
  asm volatile("s_waitcnt lgkmcnt(" #N ")"); \
  __builtin_amdgcn_sched_barrier(0); } while (0)

// ---------------------------------------------------------------------------
// 256x256x64 pipelined MFMA GEMM, free-running waves, 1 barrier / K-tile:
//   C[z] = (A[z] @ B[z]^T) * alpha + bias, A:[M][K], B:[N][K], bf16 payloads.
// 512 threads = 8 waves (2M x 4N); per-wave output 128x64 = 8x4 16x16 frags.
// LDS: A,B each 2 x 256x64 bf16 (dbuf) = 128 KiB (1 block/CU, 2 waves/SIMD).
//
// Swizzle: row stride = 128B = exact bank wrap; element (r,g16) stored at
// granule g^(r&7) -> uniform 8 lanes/bank-group on every ds_read_b128.
// gl_lds dest stays LINEAR; inverse permutation applied to the GLOBAL source
// column (srcg), reads swizzled (rule 21).
//
// Sync design: ONE boundary barrier per K-tile (buffer swap); load ledger:
//   group t P1 issues ALL 8 loads of tile t+1 into buf[(t+1)&1]
//   (order: A c0,c1, B h0 x2, B h1 x2, A c2,c3). Loop-top: vmcnt(2)
//   [first-6 of tile t landed; c2,c3 may fly] + s_barrier. Before P2's
//   ds_reads (c2,c3 rows): vmcnt(8) steady / vmcnt(0) tail.
//
// v5: intra-wave read/MFMA overlap. R5/R6's blanket lgkmcnt(0) serialized
// {8 ds_reads -> full wait -> 16 MFMA} per phase; with 2 waves/SIMD there is
// not enough cross-wave TLP to hide LDS latency+port contention (measured:
// ~50% of structural ceiling). Reads are now issued operand-paired
// (af0,bf0,af1,bf1,..) and MFMA clusters are split into groups gated by
// counted lgkmcnt (DS ops retire in-order within a wave), so later reads'
// latency hides under earlier operands' MFMAs. Per-acc MFMA order is
// unchanged (ks0 then ks1, one mfma per acc per ks) -> bit-identical.
// Requires M,N % 256 == 0, K % 64 == 0 (NT >= 2).
// ---------------------------------------------------------------------------
template<typename OutT>
__global__ __launch_bounds__(512, 2) void gemm256(
    const u16* __restrict__ A, const u16* __restrict__ B,
    const float* __restrict__ bias, const float* __restrict__ alpha_ptr,
    OutT* __restrict__ C, int K, int lda, int ldb, int ldc,
    long long sA, long long sB, long long sC)
{
  __shared__ u16 As[2][256 * 64];  // 64 KB
  __shared__ u16 Bs[2][256 * 64];  // 64 KB

  A += (long long)blockIdx.z * sA;
  B += (long long)blockIdx.z * sB;
  C += (long long)blockIdx.z * sC;

  const int tid  = threadIdx.x;
  const int m0   = blockIdx.y * 256;
  const int n0   = blockIdx.x * 256;
  const int w    = tid >> 6, lane = tid & 63;
  const int wm   = (w >> 2) * 128;   // 0 / 128
  const int wn   = (w & 3) * 64;     // 0..192
  const int lrow = lane & 15;
  const int lg   = lane >> 4;                     // k-granule 0..3
  const int xa   = lrow & 7;                      // read-side swizzle phase
  const int sr   = tid >> 3;                      // staging row-lane 0..63
  const int srcg = (tid & 7) ^ ((tid >> 3) & 7);  // inverse-swizzled src col
  const int NT   = K >> 6;

  f32x4 acc[8][4] = {};

  // staging: dest is linear (wave-uniform base + lane*16B); source column
  // carries the inverse swizzle so that logical (r,g) lands at g^(r&7).
  auto stA = [&](int t, int c) {
    u16* lb = As[t & 1];
    const int r = (sr < 32) ? (32 * c + sr) : (96 + 32 * c + sr);
    gl_lds16(A + (long long)(m0 + r) * lda + (t * 64 + srcg * 8),
             lb + r * 64 + (tid & 7) * 8);
  };
  auto stB = [&](int t, int h) {
    u16* lb = Bs[t & 1];
    #pragma unroll
    for (int l = 0; l < 2; ++l) {
      const int r = 128 * h + 64 * l + sr;
      gl_lds16(B + (long long)(n0 + r) * ldb + (t * 64 + srcg * 8),
               lb + r * 64 + (tid & 7) * 8);
    }
  };
  // issue all 8 loads of tile t (order fixes the vmcnt ledger:
  // oldest-6 = c0,c1,B; newest-2 = c2,c3)
  auto issueTile = [&](int t) {
    stA(t, 0); stA(t, 1); stB(t, 0); stB(t, 1); stA(t, 2); stA(t, 3);
  };

  // Precomputed 32-bit LDS read addresses (buf0; buf1 = +32768 B).
  const unsigned aRow = lds_off(&As[0][0]) + (wm + lrow) * 128;
  const unsigned bRow = lds_off(&Bs[0][0]) + (wn + lrow) * 128;
  const unsigned gk0  = (unsigned)((lg ^ xa) << 4);
  const unsigned gk1  = (unsigned)(((4 + lg) ^ xa) << 4);

  // --- prologue: tile0's 8 loads in flight ---
  issueTile(0);

  short8 af[4], bfr[4];
  for (int t = 0; t < NT; ++t) {
    const unsigned ab = aRow + ((t & 1) << 15);
    const unsigned bb = bRow + ((t & 1) << 15);
    const unsigned a0 = ab + gk0, a1 = ab + gk1;
    const unsigned b0 = bb + gk0, b1 = bb + gk1;

    // ---- boundary: first-6 of tile t landed (all waves), buffers swap ----
    asm volatile("s_waitcnt vmcnt(2)" ::: "memory");
    __builtin_amdgcn_s_barrier();
    __builtin_amdgcn_sched_barrier(0);

    // ---- P1: A mt0-3 ks0 + B ks0 (paired); issue ALL of tile t+1 ----
    af[0] = dsr128<0>(a0);     bfr[0] = dsr128<0>(b0);
    af[1] = dsr128<2048>(a0);  bfr[1] = dsr128<2048>(b0);
    af[2] = dsr128<4096>(a0);  bfr[2] = dsr128<4096>(b0);
    af[3] = dsr128<6144>(a0);  bfr[3] = dsr128<6144>(b0);
    if (t + 1 < NT) issueTile(t + 1);
    __builtin_amdgcn_s_setprio(1);
    LGKM(6);
    acc[0][0] = __builtin_amdgcn_mfma_f32_16x16x32_bf16(af[0], bfr[0], acc[0][0], 0, 0, 0);
    LGKM(4);
    acc[0][1] = __builtin_amdgcn_mfma_f32_16x16x32_bf16(af[0], bfr[1], acc[0][1], 0, 0, 0);
    acc[1][0] = __builtin_amdgcn_mfma_f32_16x16x32_bf16(af[1], bfr[0], acc[1][0], 0, 0, 0);
    acc[1][1] = __builtin_amdgcn_mfma_f32_16x16x32_bf16(af[1], bfr[1], acc[1][1], 0, 0, 0);
    LGKM(2);
    acc[0][2] = __builtin_amdgcn_mfma_f32_16x16x32_bf16(af[0], bfr[2], acc[0][2], 0, 0, 0);
    acc[1][2] = __builtin_amdgcn_mfma_f32_16x16x32_bf16(af[1], bfr[2], acc[1][2], 0, 0, 0);
    acc[2][0] = __builtin_amdgcn_mfma_f32_16x16x32_bf16(af[2], bfr[0], acc[2][0], 0, 0, 0);
    acc[2][1] = __builtin_amdgcn_mfma_f32_16x16x32_bf16(af[2], bfr[1], acc[2][1], 0, 0, 0);
    acc[2][2] = __builtin_amdgcn_mfma_f32_16x16x32_bf16(af[2], bfr[2], acc[2][2], 0, 0, 0);
    LGKM(0);
    acc[0][3] = __builtin_amdgcn_mfma_f32_16x16x32_bf16(af[0], bfr[3], acc[0][3], 0, 0, 0);
    acc[1][3] = __builtin_amdgcn_mfma_f32_16x16x32_bf16(af[1], bfr[3], acc[1][3], 0, 0, 0);
    acc[2][3] = __builtin_amdgcn_mfma_f32_16x16x32_bf16(af[2], bfr[3], acc[2][3], 0, 0, 0);
    acc[3][0] = __builtin_amdgcn_mfma_f32_16x16x32_bf16(af[3], bfr[0], acc[3][0], 0, 0, 0);
    acc[3][1] = __builtin_amdgcn_mfma_f32_16x16x32_bf16(af[3], bfr[1], acc[3][1], 0, 0, 0);
    acc[3][2] = __builtin_amdgcn_mfma_f32_16x16x32_bf16(af[3], bfr[2], acc[3][2], 0, 0, 0);
    acc[3][3] = __builtin_amdgcn_mfma_f32_16x16x32_bf16(af[3], bfr[3], acc[3][3], 0, 0, 0);
    __builtin_amdgcn_s_setprio(0);

    // ---- P2: A mt4-7 ks0 (c2,c3 rows: guard with counted vmcnt) ----
    if (t + 1 < NT)
      asm volatile("s_waitcnt vmcnt(8)" ::: "memory");
    else
      asm volatile("s_waitcnt vmcnt(0)" ::: "memory");
    af[0] = dsr128<8192>(a0);  af[1] = dsr128<10240>(a0);
    af[2] = dsr128<12288>(a0); af[3] = dsr128<14336>(a0);
    __builtin_amdgcn_s_setprio(1);
    LGKM(3);
    #pragma unroll
    for (int nt = 0; nt < 4; ++nt)
      acc[4][nt] = __builtin_amdgcn_mfma_f32_16x16x32_bf16(af[0], bfr[nt], acc[4][nt], 0, 0, 0);
    LGKM(2);
    #pragma unroll
    for (int nt = 0; nt < 4; ++nt)
      acc[5][nt] = __builtin_amdgcn_mfma_f32_16x16x32_bf16(af[1], bfr[nt], acc[5][nt], 0, 0, 0);
    LGKM(1);
    #pragma unroll
    for (int nt = 0; nt < 4; ++nt)
      acc[6][nt] = __builtin_amdgcn_mfma_f32_16x16x32_bf16(af[2], bfr[nt], acc[6][nt], 0, 0, 0);
    LGKM(0);
    #pragma unroll
    for (int nt = 0; nt < 4; ++nt)
      acc[7][nt] = __builtin_amdgcn_mfma_f32_16x16x32_bf16(af[3], bfr[nt], acc[7][nt], 0, 0, 0);
    __builtin_amdgcn_s_setprio(0);

    // ---- P3: A mt0-3 ks1 + B ks1 (paired) ----
    af[0] = dsr128<0>(a1);     bfr[0] = dsr128<0>(b1);
    af[1] = dsr128<2048>(a1);  bfr[1] = dsr128<2048>(b1);
    af[2] = dsr128<4096>(a1);  bfr[2] = dsr128<4096>(b1);
    af[3] = dsr128<6144>(a1);  bfr[3] = dsr128<6144>(b1);
    __builtin_amdgcn_s_setprio(1);
    LGKM(6);
    acc[0][0] = __builtin_amdgcn_mfma_f32_16x16x32_bf16(af[0], bfr[0], acc[0][0], 0, 0, 0);
    LGKM(4);
    acc[0][1] = __builtin_amdgcn_mfma_f32_16x16x32_bf16(af[0], bfr[1], acc[0][1], 0, 0, 0);
    acc[1][0] = __builtin_amdgcn_mfma_f32_16x16x32_bf16(af[1], bfr[0], acc[1][0], 0, 0, 0);
    acc[1][1] = __builtin_amdgcn_mfma_f32_16x16x32_bf16(af[1], bfr[1], acc[1][1], 0, 0, 0);
    LGKM(2);
    acc[0][2] = __builtin_amdgcn_mfma_f32_16x16x32_bf16(af[0], bfr[2], acc[0][2], 0, 0, 0);
    acc[1][2] = __builtin_amdgcn_mfma_f32_16x16x32_bf16(af[1], bfr[2], acc[1][2], 0, 0, 0);
    acc[2][0] = __builtin_amdgcn_mfma_f32_16x16x32_bf16(af[2], bfr[0], acc[2][0], 0, 0, 0);
    acc[2][1] = __builtin_amdgcn_mfma_f32_16x16x32_bf16(af[2], bfr[1], acc[2][1], 0, 0, 0);
    acc[2][2] = __builtin_amdgcn_mfma_f32_16x16x32_bf16(af[2], bfr[2], acc[2][2], 0, 0, 0);
    LGKM(0);
    acc[0][3] = __builtin_amdgcn_mfma_f32_16x16x32_bf16(af[0], bfr[3], acc[0][3], 0, 0, 0);
    acc[1][3] = __builtin_amdgcn_mfma_f32_16x16x32_bf16(af[1], bfr[3], acc[1][3], 0, 0, 0);
    acc[2][3] = __builtin_amdgcn_mfma_f32_16x16x32_bf16(af[2], bfr[3], acc[2][3], 0, 0, 0);
    acc[3][0] = __builtin_amdgcn_mfma_f32_16x16x32_bf16(af[3], bfr[0], acc[3][0], 0, 0, 0);
    acc[3][1] = __builtin_amdgcn_mfma_f32_16x16x32_bf16(af[3], bfr[1], acc[3][1], 0, 0, 0);
    acc[3][2] = __builtin_amdgcn_mfma_f32_16x16x32_bf16(af[3], bfr[2], acc[3][2], 0, 0, 0);
    acc[3][3] = __builtin_amdgcn_mfma_f32_16x16x32_bf16(af[3], bfr[3], acc[3][3], 0, 0, 0);
    __builtin_amdgcn_s_setprio(0);

    // ---- P4: A mt4-7 ks1 ----
    af[0] = dsr128<8192>(a1);  af[1] = dsr128<10240>(a1);
    af[2] = dsr128<12288>(a1); af[3] = dsr128<14336>(a1);
    __builtin_amdgcn_s_setprio(1);
    LGKM(3);
    #pragma unroll
    for (int nt = 0; nt < 4; ++nt)
      acc[4][nt] = __builtin_amdgcn_mfma_f32_16x16x32_bf16(af[0], bfr[nt], acc[4][nt], 0, 0, 0);
    LGKM(2);
    #pragma unroll
    for (int nt = 0; nt < 4; ++nt)
      acc[5][nt] = __builtin_amdgcn_mfma_f32_16x16x32_bf16(af[1], bfr[nt], acc[5][nt], 0, 0, 0);
    LGKM(1);
    #pragma unroll
    for (int nt = 0; nt < 4; ++nt)
      acc[6][nt] = __builtin_amdgcn_mfma_f32_16x16x32_bf16(af[2], bfr[nt], acc[6][nt], 0, 0, 0);
    LGKM(0);
    #pragma unroll
    for (int nt = 0; nt < 4; ++nt)
      acc[7][nt] = __builtin_amdgcn_mfma_f32_16x16x32_bf16(af[3], bfr[nt], acc[7][nt], 0, 0, 0);
    __builtin_amdgcn_s_setprio(0);
  }

  const float alpha = alpha_ptr ? *alpha_ptr : 1.0f;
  #pragma unroll
  for (int nt = 0; nt < 4; ++nt) {
    const int n = n0 + wn + nt * 16 + lrow;
    const float bv = bias ? bias[n] : 0.0f;
    #pragma unroll
    for (int mt = 0; mt < 8; ++mt)
      #pragma unroll
      for (int r = 0; r < 4; ++r) {
        const int m = m0 + wm + mt * 16 + lg * 4 + r;
        C[(long long)m * ldc + n] = OutT(acc[mt][nt][r] * alpha + bv);
      }
  }
}

// ---------------------------------------------------------------------------
// 128x128x32 MFMA GEMM (m97 structure), kept for the A^T scatter case only.
//   MA==1: A is k-strided [K][M] (sim columns); swizzled scalar LDS scatter.
//   MB==0: B direct bf16 [N][K] via global_load_lds.
// ---------------------------------------------------------------------------
template<int MA, int MB, typename OutT>
__global__ __launch_bounds__(256) void gemm128(
    const u16* __restrict__ A, const u16* __restrict__ B,
    const float* __restrict__ bias, const float* __restrict__ alpha_ptr,
    OutT* __restrict__ C, int K, int lda, int ldb, int ldc,
    long long sA, long long sB, long long sC)
{
  __shared__ u16 As[128 * 32];
  __shared__ u16 Bs[128 * 32];

  A += (long long)blockIdx.z * sA;
  B += (long long)blockIdx.z * sB;
  C += (long long)blockIdx.z * sC;

  const int tid  = threadIdx.x;
  const int m0   = blockIdx.y * 128;
  const int n0   = blockIdx.x * 128;
  const int w    = tid >> 6, lane = tid & 63;
  const int wm   = (w >> 1) * 64;
  const int wn   = (w & 1) * 64;
  const int lrow = lane & 15;
  const int lg   = lane >> 4;

  int aoff[4], boff[4];
  #pragma unroll
  for (int t = 0; t < 4; ++t) {
    const int ar = wm + t * 16 + lrow;
    const int br = wn + t * 16 + lrow;
    aoff[t] = (MA == 1) ? sw(ar, lg) : ar * 32 + lg * 8;
    boff[t] = (MB == 1) ? sw(br, lg) : br * 32 + lg * 8;
  }

  f32x4 acc[4][4] = {};

  for (int k0 = 0; k0 < K; k0 += BK) {
    if constexpr (MA == 0) {
      gl_lds16(A + (long long)(m0 + (tid >> 2)) * lda + (k0 + (tid & 3) * 8),
               As + tid * 8);
      gl_lds16(A + (long long)(m0 + 64 + (tid >> 2)) * lda + (k0 + (tid & 3) * 8),
               As + 2048 + tid * 8);
    } else {
      const int kk = tid >> 3;
      #pragma unroll
      for (int p = 0; p < 2; ++p) {
        const int rr = (tid & 7) * 8 + p * 64;
        u16 h[8];
        load8(A + (long long)(k0 + kk) * lda + (m0 + rr), h);
        #pragma unroll
        for (int j = 0; j < 8; ++j) As[sw(rr + j, kk >> 3) + (kk & 7)] = h[j];
      }
    }
    if constexpr (MB == 0) {
      gl_lds16(B + (long long)(n0 + (tid >> 2)) * ldb + (k0 + (tid & 3) * 8),
               Bs + tid * 8);
      gl_lds16(B + (long long)(n0 + 64 + (tid >> 2)) * ldb + (k0 + (tid & 3) * 8),
               Bs + 2048 + tid * 8);
    } else {
      const int kk = tid >> 3;
      #pragma unroll
      for (int p = 0; p < 2; ++p) {
        const int rr = (tid & 7) * 8 + p * 64;
        u16 h[8];
        load8(B + (long long)(k0 + kk) * ldb + (n0 + rr), h);
        #pragma unroll
        for (int j = 0; j < 8; ++j) Bs[sw(rr + j, kk >> 3) + (kk & 7)] = h[j];
      }
    }
    __syncthreads();

    short8 af[4], bf[4];
    #pragma unroll
    for (int t = 0; t < 4; ++t) af[t] = *(const short8*)(As + aoff[t]);
    #pragma unroll
    for (int t = 0; t < 4; ++t) bf[t] = *(const short8*)(Bs + boff[t]);
    #pragma unroll
    for (int mt = 0; mt < 4; ++mt)
      #pragma unroll
      for (int nt = 0; nt < 4; ++nt)
        acc[mt][nt] = __builtin_amdgcn_mfma_f32_16x16x32_bf16(
            af[mt], bf[nt], acc[mt][nt], 0, 0, 0);
    __syncthreads();
  }

  const float alpha = alpha_ptr ? *alpha_ptr : 1.0f;
  #pragma unroll
  for (int nt = 0; nt < 4; ++nt) {
    const int n = n0 + wn + nt * 16 + lrow;
    const float bv = bias ? bias[n] : 0.0f;
    #pragma unroll
    for (int mt = 0; mt < 4; ++mt) {
      #pragma unroll
      for (int r = 0; r < 4; ++r) {
        const int m = m0 + wm + mt * 16 + lg * 4 + r;
        C[(long long)m * ldc + n] = OutT(acc[mt][nt][r] * alpha + bv);
      }
    }
  }
}

// ---------------------------------------------------------------------------
// Tiled 64x64 transpose with optional fp32->bf16 convert.
// ---------------------------------------------------------------------------
template<typename T>
__global__ __launch_bounds__(256) void transpose_kernel(
    const T* __restrict__ in, u16* __restrict__ out, int R, int C,
    long long sIn, long long sOut)
{
  __shared__ u16 t[64][66];
  in  += (long long)blockIdx.z * sIn;
  out += (long long)blockIdx.z * sOut;
  const int r0 = blockIdx.y * 64, c0 = blockIdx.x * 64;
  const int tid = threadIdx.x;
  const int rr = tid >> 3, cc = (tid & 7) * 8;
  #pragma unroll
  for (int p = 0; p < 2; ++p) {
    union { uint4 u; unsigned w[4]; u16 h[8]; } v;
    const int row = rr + p * 32;
    load8(in + (long long)(r0 + row) * C + (c0 + cc), v.h);
    #pragma unroll
    for (int k = 0; k < 4; ++k)
      *(unsigned*)&t[row][cc + k * 2] = v.w[k];
  }
  __syncthreads();
  #pragma unroll
  for (int p = 0; p < 2; ++p) {
    const int oc = (tid >> 3) + p * 32;
    const int rc = (tid & 7) * 8;
    union { uint4 u; u16 h[8]; } g;
    #pragma unroll
    for (int j = 0; j < 8; ++j) g.h[j] = t[rc + j][oc];
    *(uint4*)(out + (long long)(c0 + oc) * R + (r0 + rc)) = g.u;
  }
}

// ---------------------------------------------------------------------------
// Elementwise fp32 -> bf16 convert (row-major), 8 elems/thread/iter.
// ---------------------------------------------------------------------------
__global__ __launch_bounds__(256) void cvt_kernel(
    const float* __restrict__ in, u16* __restrict__ out, int n8)
{
  const int stride = gridDim.x * 256;
  for (int i = blockIdx.x * 256 + threadIdx.x; i < n8; i += stride) {
    union { uint4 u; u16 h[8]; } v;
    load8(in + (long long)i * 8, v.h);
    *(uint4*)(out + (long long)i * 8) = v.u;
  }
}

// ---------------------------------------------------------------------------
// LayerNorm + ReLU over rows of 768 fp32 -> OutT. ReLU propagates NaN.
// ---------------------------------------------------------------------------
template<typename OutT>
__global__ __launch_bounds__(256) void ln_relu_kernel(
    const float* __restrict__ x, const float* __restrict__ g,
    const float* __restrict__ beta, OutT* __restrict__ out)
{
  __shared__ float sa[4], sb[4];
  const float* xr = x + (long long)blockIdx.x * 768;
  float v[3]; float s = 0.f, ss = 0.f;
  #pragma unroll
  for (int j = 0; j < 3; ++j) {
    v[j] = xr[threadIdx.x + j * 256];
    s += v[j]; ss += v[j] * v[j];
  }
  #pragma unroll
  for (int off = 32; off; off >>= 1) {
    s  += __shfl_down(s, off);
    ss += __shfl_down(ss, off);
  }
  const int w = threadIdx.x >> 6, lane = threadIdx.x & 63;
  if (!lane) { sa[w] = s; sb[w] = ss; }
  __syncthreads();
  s  = sa[0] + sa[1] + sa[2] + sa[3];
  ss = sb[0] + sb[1] + sb[2] + sb[3];
  const float mean = s * (1.f / 768.f);
  const float var  = ss * (1.f / 768.f) - mean * mean;
  const float rst  = rsqrtf(var + 1e-5f);
  OutT* orow = out + (long long)blockIdx.x * 768;
  #pragma unroll
  for (int j = 0; j < 3; ++j) {
    const int idx = threadIdx.x + j * 256;
    const float yv = (v[j] - mean) * rst * g[idx] + beta[idx];
    const float rv = (yv <= 0.f) ? 0.f : yv;  // NaN -> yv (propagates)
    orow[idx] = OutT(rv);
  }
}

// ---------------------------------------------------------------------------
// In-place row softmax over 2048 bf16 values (fp32 math)
// ---------------------------------------------------------------------------
__global__ __launch_bounds__(256) void softmax_kernel(u16* __restrict__ sim)
{
  __shared__ float sm[4], ssum[4];
  u16* row = sim + (long long)blockIdx.x * 2048;
  union { uint4 u; u16 h[8]; } v;
  v.u = *(const uint4*)(row + threadIdx.x * 8);
  float f[8]; float mx = -1e30f;
  #pragma unroll
  for (int j = 0; j < 8; ++j) { f[j] = b2f(v.h[j]); mx = fmaxf(mx, f[j]); }
  #pragma unroll
  for (int off = 32; off; off >>= 1) mx = fmaxf(mx, __shfl_down(mx, off));
  const int w = threadIdx.x >> 6, lane = threadIdx.x & 63;
  if (!lane) sm[w] = mx;
  __syncthreads();
  mx = fmaxf(fmaxf(sm[0], sm[1]), fmaxf(sm[2], sm[3]));
  float s = 0.f;
  #pragma unroll
  for (int j = 0; j < 8; ++j) { f[j] = __expf(f[j] - mx); s += f[j]; }
  #pragma unroll
  for (int off = 32; off; off >>= 1) s += __shfl_down(s, off);
  if (!lane) ssum[w] = s;
  __syncthreads();
  s = ssum[0] + ssum[1] + ssum[2] + ssum[3];
  const float inv = 1.f / s;
  #pragma unroll
  for (int j = 0; j < 8; ++j) v.h[j] = f2b(f[j] * inv);
  *(uint4*)(row + threadIdx.x * 8) = v.u;
}

// ---------------------------------------------------------------------------
// claw mean, two deterministic stages
// ---------------------------------------------------------------------------
__global__ __launch_bounds__(256) void claw_partial_kernel(
    const float* __restrict__ claw, float* __restrict__ partial, int n)
{
  __shared__ float sa[4];
  float s = 0.f;
  const int nv = n >> 2;
  for (int i = blockIdx.x * 256 + threadIdx.x; i < nv; i += 64 * 256) {
    float4 v = ((const float4*)claw)[i];
    s += v.x + v.y + v.z + v.w;
  }
  #pragma unroll
  for (int off = 32; off; off >>= 1) s += __shfl_down(s, off);
  const int w = threadIdx.x >> 6, lane = threadIdx.x & 63;
  if (!lane) sa[w] = s;
  __syncthreads();
  if (threadIdx.x == 0)
    partial[blockIdx.x] = sa[0] + sa[1] + sa[2] + sa[3];
}

__global__ void claw_final_kernel(
    const float* __restrict__ partial, float* __restrict__ scale, float inv)
{
  float s = partial[threadIdx.x];
  #pragma unroll
  for (int off = 32; off; off >>= 1) s += __shfl_down(s, off);
  if (threadIdx.x == 0) *scale = s * inv;
}

// ---------------------------------------------------------------------------
extern "C" void kernel_launch(void* const* d_in, const int* in_sizes, int n_in,
                              void* d_out, int out_size, void* d_ws, size_t ws_size,
                              hipStream_t stream)
{
  const float* vis   = (const float*)d_in[0];
  const float* lang  = (const float*)d_in[1];
  const float* vW    = (const float*)d_in[2];
  const float* vb    = (const float*)d_in[3];
  const float* vg    = (const float*)d_in[4];
  const float* vbeta = (const float*)d_in[5];
  const float* lW    = (const float*)d_in[6];
  const float* lb    = (const float*)d_in[7];
  const float* lg    = (const float*)d_in[8];
  const float* lbeta = (const float*)d_in[9];
  const float* claw  = (const float*)d_in[10];
  const float* oW    = (const float*)d_in[11];
  const float* ob    = (const float*)d_in[12];
  const float* og    = (const float*)d_in[13];
  const float* obeta = (const float*)d_in[14];
  float* out = (float*)d_out;

  constexpr int NB = 8, S = 2048, D = 768;
  constexpr int R = NB * S;                       // 16384
  constexpr long long SD = (long long)S * D;      // 1,572,864
  constexpr long long SS = (long long)S * S;      // 4,194,304
  const int nclaw = in_sizes[10];
  const float claw_inv = 1.0f / ((float)nclaw * 0.07f);
  const dim3 blk(256);
  const dim3 blk5(512);

  // Workspace layout (peak 167,772,432 B == proven floor from prior rounds).
  char* ws = (char*)d_ws;
  u16*   vp    = (u16*)  (ws);
  u16*   lp    = (u16*)  (ws + 25165824);
  u16*   visb  = (u16*)  (ws + 50331648);
  u16*   vpT   = (u16*)  (ws + 50331648);
  u16*   langb = (u16*)  (ws + 75497472);
  u16*   lpT   = (u16*)  (ws + 75497472);
  u16*   sim   = (u16*)  (ws + 100663296);
  float* y     = (float*)(ws + 100663296);
  u16*   vWT   = (u16*)  (ws + 150994944);
  u16*   lWT   = vWT + 589824;
  u16*   oWT   = (u16*)  (ws + 150994944);
  u16*   comb  = (u16*)  (ws);
  float* scale   = (float*)(ws + 167772160);
  float* partial = (float*)(ws + 167772176);

  claw_partial_kernel<<<64, blk, 0, stream>>>(claw, partial, nclaw);
  claw_final_kernel<<<1, 64, 0, stream>>>(partial, scale, claw_inv);

  // Weight transposes: W[k][n] fp32 -> WT[n][k] bf16 (direct B operands)
  transpose_kernel<float><<<dim3(12, 12, 1), blk, 0, stream>>>(
      vW, vWT, D, D, 0, 0);
  transpose_kernel<float><<<dim3(12, 12, 1), blk, 0, stream>>>(
      lW, lWT, D, D, 0, 0);

  // vision: visb = bf16(vis); y = visb @ vWT^T + vb; vp = relu(LN(y)); vpT
  cvt_kernel<<<2048, blk, 0, stream>>>(vis, visb, (int)(R * D / 8));
  gemm256<float><<<dim3(D / 256, R / 256, 1), blk5, 0, stream>>>(
      visb, vWT, vb, nullptr, y, D, D, D, D, 0, 0, 0);
  ln_relu_kernel<__hip_bfloat16><<<R, blk, 0, stream>>>(
      y, vg, vbeta, (__hip_bfloat16*)vp);
  transpose_kernel<u16><<<dim3(D / 64, S / 64, NB), blk, 0, stream>>>(
      vp, vpT, S, D, SD, SD);

  // language
  cvt_kernel<<<2048, blk, 0, stream>>>(lang, langb, (int)(R * D / 8));
  gemm256<float><<<dim3(D / 256, R / 256, 1), blk5, 0, stream>>>(
      langb, lWT, lb, nullptr, y, D, D, D, D, 0, 0, 0);
  ln_relu_kernel<__hip_bfloat16><<<R, blk, 0, stream>>>(
      y, lg, lbeta, (__hip_bfloat16*)lp);
  transpose_kernel<u16><<<dim3(D / 64, S / 64, NB), blk, 0, stream>>>(
      lp, lpT, S, D, SD, SD);

  // sim[z] = (vp[z] @ lp[z]^T) * scale
  gemm256<__hip_bfloat16><<<dim3(S / 256, S / 256, NB), blk5, 0, stream>>>(
      vp, lp, nullptr, scale, (__hip_bfloat16*)sim, D, D, D, S, SD, SD, SS);
  softmax_kernel<<<R, blk, 0, stream>>>(sim);

  // aligned_vision[z] = A[z] @ vp[z] -> comb[:, 0:768]  (direct via vpT)
  gemm256<__hip_bfloat16><<<dim3(D / 256, S / 256, NB), blk5, 0, stream>>>(
      sim, vpT, nullptr, nullptr, (__hip_bfloat16*)comb,
      S, S, S, 2 * D, SS, SD, 2 * SD);
  // aligned_language[z] = A[z]^T @ lp[z] -> comb[:, 768:1536]
  // (A scatter over sim; B direct via lpT) - stays on the 128^2 kernel.
  gemm128<1, 0, __hip_bfloat16><<<dim3(D / 128, S / 128, NB), blk, 0, stream>>>(
      sim, lpT, nullptr, nullptr, (__hip_bfloat16*)comb + D,
      S, S, S, 2 * D, SS, SD, 2 * SD);

  // oWT (sim region dead past here except y overlay)
  transpose_kernel<float><<<dim3(12, 24, 1), blk, 0, stream>>>(
      oW, oWT, 2 * D, D, 0, 0);

  // out = relu(LN(comb @ oWT^T + ob))
  gemm256<float><<<dim3(D / 256, R / 256, 1), blk5, 0, stream>>>(
      comb, oWT, ob, nullptr, y, 2 * D, 2 * D, 2 * D, D, 0, 0, 0);
  ln_relu_kernel<float><<<R, blk, 0, stream>>>(y, og, obeta, out);
}